// Round 2
// baseline (330.625 us; speedup 1.0000x reference)
//
#include <hip/hip_runtime.h>
#include <hip/hip_bf16.h>
#include <stdint.h>

#define S_LEN 2048
#define EMB   1024
#define NHEAD 16
#define HDIM  64
#define BATCH 2

typedef __bf16 bf16x8 __attribute__((ext_vector_type(8)));
typedef float  f32x4  __attribute__((ext_vector_type(4)));

// async global->LDS, 16B per lane; LDS dest = wave-uniform base + lane*16
__device__ __forceinline__ void gll16(const void* g, void* l) {
  __builtin_amdgcn_global_load_lds(
      (const __attribute__((address_space(1))) void*)g,
      (__attribute__((address_space(3))) void*)l,
      16, 0, 0);
}

// ---------------- kernel 0: fp32 -> bf16 cast (inputs + weights) ------------
__global__ void __launch_bounds__(256) cast_kernel(
    const float* __restrict__ s0, const float* __restrict__ s1, const float* __restrict__ s2,
    const float* __restrict__ s3, const float* __restrict__ s4, const float* __restrict__ s5,
    const float* __restrict__ s6,
    __hip_bfloat16* __restrict__ d0, __hip_bfloat16* __restrict__ d1,
    __hip_bfloat16* __restrict__ d2, __hip_bfloat16* __restrict__ d3,
    __hip_bfloat16* __restrict__ d4, __hip_bfloat16* __restrict__ d5,
    __hip_bfloat16* __restrict__ d6) {
  const int z = blockIdx.y;
  const float* s = (z == 0) ? s0 : (z == 1) ? s1 : (z == 2) ? s2 : (z == 3) ? s3
                 : (z == 4) ? s4 : (z == 5) ? s5 : s6;
  __hip_bfloat16* d = (z == 0) ? d0 : (z == 1) ? d1 : (z == 2) ? d2 : (z == 3) ? d3
                    : (z == 4) ? d4 : (z == 5) ? d5 : d6;
  const int n = (z < 3) ? (BATCH * S_LEN * EMB) : (EMB * EMB);
  const size_t i = ((size_t)blockIdx.x * 256 + threadIdx.x) * 16;
  if (i >= (size_t)n) return;
  __hip_bfloat16 tmp[16];
#pragma unroll
  for (int j = 0; j < 4; ++j) {
    const float4 v = *(const float4*)(s + i + j * 4);
    tmp[j * 4 + 0] = __float2bfloat16(v.x);
    tmp[j * 4 + 1] = __float2bfloat16(v.y);
    tmp[j * 4 + 2] = __float2bfloat16(v.z);
    tmp[j * 4 + 3] = __float2bfloat16(v.w);
  }
  *(bf16x8*)(d + i)     = *(bf16x8*)&tmp[0];
  *(bf16x8*)(d + i + 8) = *(bf16x8*)&tmp[8];
}

// ---------------- kernel 1: mask tile flags (64q x 128k tiles) ----------------
__global__ void __launch_bounds__(256) mask_flags_kernel(const int* __restrict__ mask,
                                                         unsigned* __restrict__ flags) {
  const int kt = blockIdx.x, qt = blockIdx.y, b = blockIdx.z;
  const int t = threadIdx.x;
  const int* base = mask + ((size_t)b * S_LEN + (size_t)qt * 64) * S_LEN + (size_t)kt * 128;
  int ok = 1;
#pragma unroll
  for (int p = 0; p < 8; ++p) {
    int idx = p * 256 + t;              // 2048 int4 chunks: 64 rows x 32
    int row = idx >> 5, c4 = idx & 31;
    const int4 v = *(const int4*)(base + (size_t)row * S_LEN + c4 * 4);
    ok &= (v.x != 0) & (v.y != 0) & (v.z != 0) & (v.w != 0);
  }
  unsigned long long bl = __ballot(ok);
  __shared__ unsigned long long bw[4];
  bw[t >> 6] = bl;
  __syncthreads();
  if (t == 0) {
    unsigned all = ((bw[0] & bw[1] & bw[2] & bw[3]) == ~0ull) ? 1u : 0u;
    flags[((size_t)b * 32 + qt) * 16 + kt] = all;
  }
}

// ---------------- kernel 2/4: GEMM  C = A @ W^T + bias  (m97 structure) ------
// modes: 0 -> Q (scale 1/8, bf16 [b,h,s,d]); 1 -> K (bf16 [b,h,s,d]);
//        2 -> V^T (bf16 [b,h,d,s]); 3 -> plain row-major [m,n], fp32 out
__global__ void __launch_bounds__(256, 2)
gemm_kernel(const __hip_bfloat16* __restrict__ A0, const __hip_bfloat16* __restrict__ A1,
            const __hip_bfloat16* __restrict__ A2,
            const __hip_bfloat16* __restrict__ W0, const __hip_bfloat16* __restrict__ W1,
            const __hip_bfloat16* __restrict__ W2,
            const float* __restrict__ b0, const float* __restrict__ b1,
            const float* __restrict__ b2,
            void* __restrict__ O0, void* __restrict__ O1, void* __restrict__ O2, int qkv) {
  __shared__ __align__(16) __hip_bfloat16 As[128 * 32];
  __shared__ __align__(16) __hip_bfloat16 Bs[128 * 32];

  const int z = blockIdx.z;
  const __hip_bfloat16* A  = (z == 0) ? A0 : ((z == 1) ? A1 : A2);
  const __hip_bfloat16* W  = (z == 0) ? W0 : ((z == 1) ? W1 : W2);
  const float* bi          = (z == 0) ? b0 : ((z == 1) ? b1 : b2);
  void* O                  = (z == 0) ? O0 : ((z == 1) ? O1 : O2);
  const int mode = qkv ? z : 3;

  const int t = threadIdx.x;
  const int w = t >> 6, lane = t & 63, quad = lane >> 4, l15 = lane & 15;
  const int m0 = blockIdx.y * 128, n0 = blockIdx.x * 128;
  const int wr = w >> 1, wc = w & 1;

  f32x4 acc[4][4];
#pragma unroll
  for (int i = 0; i < 4; ++i)
#pragma unroll
    for (int j = 0; j < 4; ++j) acc[i][j] = (f32x4)0.0f;

  for (int k0 = 0; k0 < EMB; k0 += 32) {
    __syncthreads();
#pragma unroll
    for (int rnd = 0; rnd < 2; ++rnd) {
      int idx = rnd * 256 + t;                 // 512 chunks: row=idx/4, 8-elem blk=idx%4
      gll16(A + (size_t)(m0 + (idx >> 2)) * EMB + k0 + ((idx & 3) << 3),
            &As[(rnd * 256 + (w << 6)) * 8]);
      gll16(W + (size_t)(n0 + (idx >> 2)) * EMB + k0 + ((idx & 3) << 3),
            &Bs[(rnd * 256 + (w << 6)) * 8]);
    }
    __syncthreads();

    bf16x8 af[4], bfr[4];
#pragma unroll
    for (int i = 0; i < 4; ++i)
      af[i] = *(const bf16x8*)&As[(wr * 64 + i * 16 + l15) * 32 + quad * 8];
#pragma unroll
    for (int j = 0; j < 4; ++j)
      bfr[j] = *(const bf16x8*)&Bs[(wc * 64 + j * 16 + l15) * 32 + quad * 8];
#pragma unroll
    for (int i = 0; i < 4; ++i)
#pragma unroll
      for (int j = 0; j < 4; ++j)
        acc[i][j] = __builtin_amdgcn_mfma_f32_16x16x32_bf16(af[i], bfr[j], acc[i][j], 0, 0, 0);
  }

  // epilogue: C row = m0+wr*64+i*16+quad*4+r (token), col = n0+wc*64+j*16+l15 (feature)
#pragma unroll
  for (int j = 0; j < 4; ++j) {
    const int ng = n0 + wc * 64 + j * 16 + l15;
    const float bb = bi[ng];
#pragma unroll
    for (int i = 0; i < 4; ++i) {
#pragma unroll
      for (int r = 0; r < 4; ++r) {
        const int mg = m0 + wr * 64 + i * 16 + quad * 4 + r;
        float v = acc[i][j][r] + bb;
        if (mode == 0) {
          int b = mg >> 11, s = mg & 2047, h = ng >> 6, d = ng & 63;
          ((__hip_bfloat16*)O)[(((size_t)b * NHEAD + h) * S_LEN + s) * HDIM + d] =
              __float2bfloat16(v * 0.125f);
        } else if (mode == 1) {
          int b = mg >> 11, s = mg & 2047, h = ng >> 6, d = ng & 63;
          ((__hip_bfloat16*)O)[(((size_t)b * NHEAD + h) * S_LEN + s) * HDIM + d] =
              __float2bfloat16(v);
        } else if (mode == 2) {
          int b = mg >> 11, s = mg & 2047, h = ng >> 6, d = ng & 63;
          ((__hip_bfloat16*)O)[(((size_t)b * NHEAD + h) * HDIM + d) * S_LEN + s] =
              __float2bfloat16(v);
        } else {
          ((float*)O)[(size_t)mg * EMB + ng] = v;   // fp32 final output
        }
      }
    }
  }
}

// ---------------- kernel 3: flash attention, no-max online softmax ----------
// block = 4 waves; wave w owns q rows [q0+16w, q0+16w+16); loop over 128-key tiles.
// XOR swizzle on 16B blocks breaks the full-bank-wrap row strides.
__global__ void __launch_bounds__(256, 2)
flash_kernel(const __hip_bfloat16* __restrict__ qws, const __hip_bfloat16* __restrict__ kws,
             const __hip_bfloat16* __restrict__ vtws, const int* __restrict__ responses,
             const int* __restrict__ mask, const float* __restrict__ Wm,
             const unsigned* __restrict__ flags, __hip_bfloat16* __restrict__ att) {
  __shared__ __align__(16) __hip_bfloat16 Ks[128 * 64];   // [key][d],  8 blocks/row, swizzled
  __shared__ __align__(16) __hip_bfloat16 Vs[64 * 128];   // [d][key], 16 blocks/row, swizzled
  __shared__ __align__(16) __hip_bfloat16 Ps[64 * 128];   // [q][key], 16 blocks/row, swizzled

  const int t = threadIdx.x;
  const int w = t >> 6, lane = t & 63, quad = lane >> 4, l15 = lane & 15;
  const int qt = blockIdx.x, h = blockIdx.y, b = blockIdx.z;
  const int bh = b * NHEAD + h;
  const int q0 = qt * 64;

  // Q fragments (A-layout), held in registers for the whole kernel
  const __hip_bfloat16* qbase = qws + ((size_t)bh * S_LEN + q0) * HDIM;
  bf16x8 qf[2];
#pragma unroll
  for (int ks = 0; ks < 2; ++ks)
    qf[ks] = *(const bf16x8*)(qbase + (size_t)(w * 16 + l15) * HDIM + ks * 32 + quad * 8);

  const float nch = -Wm[h] * (1.0f / 16.0f);
  float rqf[4];
#pragma unroll
  for (int r = 0; r < 4; ++r)
    rqf[r] = (float)responses[b * S_LEN + q0 + w * 16 + quad * 4 + r];

  float lsum[4] = {0.f, 0.f, 0.f, 0.f};
  f32x4 acc_o[4];
#pragma unroll
  for (int dt = 0; dt < 4; ++dt) acc_o[dt] = (f32x4)0.0f;

  for (int kt = 0; kt < S_LEN / 128; ++kt) {
    __syncthreads();
#pragma unroll
    for (int p = 0; p < 4; ++p) {
      int idx = p * 256 + t;
      {  // K tile: row = idx/8, swizzled source block
        int row = idx >> 3, gcb = (idx & 7) ^ (row & 7);
        gll16(kws + ((size_t)bh * S_LEN + kt * 128 + row) * HDIM + gcb * 8,
              &Ks[(p * 256 + (w << 6)) * 8]);
      }
      {  // V^T tile: row = idx/16
        int row = idx >> 4, gcb = (idx & 15) ^ (row & 7);
        gll16(vtws + ((size_t)bh * HDIM + row) * S_LEN + kt * 128 + gcb * 8,
              &Vs[(p * 256 + (w << 6)) * 8]);
      }
    }
    __syncthreads();

    // QK^T: C[q][key] for this wave's 16 q rows, 8 key tiles of 16
    f32x4 sc[8];
#pragma unroll
    for (int ct = 0; ct < 8; ++ct) {
      const int rowk = ct * 16 + l15;
      bf16x8 kf0 = *(const bf16x8*)&Ks[rowk * 64 + (((0 * 4 + quad) ^ (l15 & 7)) << 3)];
      bf16x8 kf1 = *(const bf16x8*)&Ks[rowk * 64 + (((1 * 4 + quad) ^ (l15 & 7)) << 3)];
      sc[ct] = __builtin_amdgcn_mfma_f32_16x16x32_bf16(qf[0], kf0, (f32x4)0.0f, 0, 0, 0);
      sc[ct] = __builtin_amdgcn_mfma_f32_16x16x32_bf16(qf[1], kf1, sc[ct], 0, 0, 0);
    }

    const unsigned fl = flags[((size_t)b * 32 + qt) * 16 + kt];

    // bias + exp (no max subtraction: |scores| bounded ~4), write P (bf16) to LDS
#pragma unroll
    for (int ct = 0; ct < 8; ++ct) {
      const float rk = (float)responses[b * S_LEN + kt * 128 + ct * 16 + l15];
      const int cb = (ct << 1) | (l15 >> 3);
#pragma unroll
      for (int r = 0; r < 4; ++r) {
        const float dd = rqf[r] - rk;
        const float sb = fmaf(nch * dd, dd, sc[ct][r]);
        float p = __builtin_amdgcn_exp2f(sb * 1.4426950408889634f);
        if (!fl) {  // slow path: per-element mask (not taken for all-ones mask)
          int mq = mask[((size_t)b * S_LEN + q0 + w * 16 + quad * 4 + r) * S_LEN +
                        kt * 128 + ct * 16 + l15];
          p = mq ? p : 0.0f;
        }
        lsum[r] += p;
        const int prow = w * 16 + quad * 4 + r;
        Ps[prow * 128 + ((cb ^ (prow & 7)) << 3) + (l15 & 7)] = __float2bfloat16(p);
      }
    }

    // PV: C[q][d] += P[q][key] * V^T[d][key]   (wave-private P band, no barrier)
#pragma unroll
    for (int kst = 0; kst < 4; ++kst) {
      const int prow = w * 16 + l15;
      bf16x8 pf = *(const bf16x8*)&Ps[prow * 128 + ((((kst << 2) + quad) ^ (l15 & 7)) << 3)];
#pragma unroll
      for (int dt = 0; dt < 4; ++dt) {
        const int vrow = dt * 16 + l15;
        bf16x8 vf = *(const bf16x8*)&Vs[vrow * 128 + ((((kst << 2) + quad) ^ (l15 & 7)) << 3)];
        acc_o[dt] = __builtin_amdgcn_mfma_f32_16x16x32_bf16(pf, vf, acc_o[dt], 0, 0, 0);
      }
    }
  }

  // finalize: row sums across the 16 lanes of each quad, normalize, store
#pragma unroll
  for (int r = 0; r < 4; ++r) {
#pragma unroll
    for (int off = 1; off < 16; off <<= 1) lsum[r] += __shfl_xor(lsum[r], off, 64);
    lsum[r] = 1.0f / lsum[r];
  }
#pragma unroll
  for (int dt = 0; dt < 4; ++dt) {
#pragma unroll
    for (int r = 0; r < 4; ++r) {
      float v = acc_o[dt][r] * lsum[r];
      att[((size_t)b * S_LEN + q0 + w * 16 + quad * 4 + r) * EMB + h * HDIM + dt * 16 + l15] =
          __float2bfloat16(v);
    }
  }
}

// ---------------------------------------------------------------------------
extern "C" void kernel_launch(void* const* d_in, const int* in_sizes, int n_in,
                              void* d_out, int out_size, void* d_ws, size_t ws_size,
                              hipStream_t stream) {
  const float* query = (const float*)d_in[0];
  const float* key_  = (const float*)d_in[1];
  const float* value = (const float*)d_in[2];
  const int* responses = (const int*)d_in[3];
  const int* mask      = (const int*)d_in[4];
  const float* Wq = (const float*)d_in[5];
  const float* bq = (const float*)d_in[6];
  const float* Wk = (const float*)d_in[7];
  const float* bk = (const float*)d_in[8];
  const float* Wv = (const float*)d_in[9];
  const float* bv = (const float*)d_in[10];
  const float* Wo = (const float*)d_in[11];
  const float* bo = (const float*)d_in[12];
  const float* Wm = (const float*)d_in[13];
  // d_in[14] (bm): per-row constant under softmax -> exactly cancels; unused.

  __hip_bfloat16* ws = (__hip_bfloat16*)d_ws;
  const size_t NTOK = (size_t)BATCH * S_LEN * EMB;  // 4 Mi elements
  const size_t NW   = (size_t)EMB * EMB;            // 1 Mi elements
  __hip_bfloat16* qcast = ws;
  __hip_bfloat16* kcast = ws + NTOK;
  __hip_bfloat16* vcast = ws + 2 * NTOK;
  __hip_bfloat16* wqb   = ws + 3 * NTOK;
  __hip_bfloat16* wkb   = wqb + NW;
  __hip_bfloat16* wvb   = wqb + 2 * NW;
  __hip_bfloat16* wob   = wqb + 3 * NW;
  __hip_bfloat16* qws   = wqb + 4 * NW;
  __hip_bfloat16* kws   = qws + NTOK;
  __hip_bfloat16* vtws  = qws + 2 * NTOK;
  __hip_bfloat16* att   = qws + 3 * NTOK;
  unsigned* flags       = (unsigned*)(qws + 4 * NTOK);
  float* out            = (float*)d_out;

  cast_kernel<<<dim3(1024, 7), 256, 0, stream>>>(query, key_, value, Wq, Wk, Wv, Wo,
                                                 qcast, kcast, vcast, wqb, wkb, wvb, wob);
  mask_flags_kernel<<<dim3(16, 32, 2), 256, 0, stream>>>(mask, flags);
  gemm_kernel<<<dim3(8, 32, 3), 256, 0, stream>>>(qcast, kcast, vcast, wqb, wkb, wvb,
                                                  bq, bk, bv, qws, kws, vtws, 1);
  flash_kernel<<<dim3(32, 16, 2), 256, 0, stream>>>(qws, kws, vtws, responses, mask,
                                                    Wm, flags, att);
  gemm_kernel<<<dim3(8, 32, 1), 256, 0, stream>>>(att, att, att, wob, wob, wob,
                                                  bo, bo, bo, out, out, out, 0);
}

// Round 3
// 295.164 us; speedup vs baseline: 1.1201x; 1.1201x over previous
//
#include <hip/hip_runtime.h>
#include <hip/hip_bf16.h>
#include <stdint.h>

#define S_LEN 2048
#define EMB   1024
#define NHEAD 16
#define HDIM  64
#define BATCH 2

typedef __bf16 bf16x8 __attribute__((ext_vector_type(8)));
typedef float  f32x4  __attribute__((ext_vector_type(4)));

// async global->LDS, 16B per lane; LDS dest = wave-uniform base + lane*16
__device__ __forceinline__ void gll16(const void* g, void* l) {
  __builtin_amdgcn_global_load_lds(
      (const __attribute__((address_space(1))) void*)g,
      (__attribute__((address_space(3))) void*)l,
      16, 0, 0);
}

// ---------------- kernel 0: fp32 -> bf16 cast (inputs + weights) ------------
__global__ void __launch_bounds__(256) cast_kernel(
    const float* __restrict__ s0, const float* __restrict__ s1, const float* __restrict__ s2,
    const float* __restrict__ s3, const float* __restrict__ s4, const float* __restrict__ s5,
    const float* __restrict__ s6,
    __hip_bfloat16* __restrict__ d0, __hip_bfloat16* __restrict__ d1,
    __hip_bfloat16* __restrict__ d2, __hip_bfloat16* __restrict__ d3,
    __hip_bfloat16* __restrict__ d4, __hip_bfloat16* __restrict__ d5,
    __hip_bfloat16* __restrict__ d6) {
  const int z = blockIdx.y;
  const float* s = (z == 0) ? s0 : (z == 1) ? s1 : (z == 2) ? s2 : (z == 3) ? s3
                 : (z == 4) ? s4 : (z == 5) ? s5 : s6;
  __hip_bfloat16* d = (z == 0) ? d0 : (z == 1) ? d1 : (z == 2) ? d2 : (z == 3) ? d3
                    : (z == 4) ? d4 : (z == 5) ? d5 : d6;
  const int n = (z < 3) ? (BATCH * S_LEN * EMB) : (EMB * EMB);
  const size_t i = ((size_t)blockIdx.x * 256 + threadIdx.x) * 16;
  if (i >= (size_t)n) return;
  __hip_bfloat16 tmp[16];
#pragma unroll
  for (int j = 0; j < 4; ++j) {
    const float4 v = *(const float4*)(s + i + j * 4);
    tmp[j * 4 + 0] = __float2bfloat16(v.x);
    tmp[j * 4 + 1] = __float2bfloat16(v.y);
    tmp[j * 4 + 2] = __float2bfloat16(v.z);
    tmp[j * 4 + 3] = __float2bfloat16(v.w);
  }
  *(bf16x8*)(d + i)     = *(bf16x8*)&tmp[0];
  *(bf16x8*)(d + i + 8) = *(bf16x8*)&tmp[8];
}

// ---------------- kernel 1: mask tile flags (64q x 128k tiles) ----------------
__global__ void __launch_bounds__(256) mask_flags_kernel(const int* __restrict__ mask,
                                                         unsigned* __restrict__ flags) {
  const int kt = blockIdx.x, qt = blockIdx.y, b = blockIdx.z;
  const int t = threadIdx.x;
  const int* base = mask + ((size_t)b * S_LEN + (size_t)qt * 64) * S_LEN + (size_t)kt * 128;
  int ok = 1;
#pragma unroll
  for (int p = 0; p < 8; ++p) {
    int idx = p * 256 + t;
    int row = idx >> 5, c4 = idx & 31;
    const int4 v = *(const int4*)(base + (size_t)row * S_LEN + c4 * 4);
    ok &= (v.x != 0) & (v.y != 0) & (v.z != 0) & (v.w != 0);
  }
  unsigned long long bl = __ballot(ok);
  __shared__ unsigned long long bw[4];
  bw[t >> 6] = bl;
  __syncthreads();
  if (t == 0) {
    unsigned all = ((bw[0] & bw[1] & bw[2] & bw[3]) == ~0ull) ? 1u : 0u;
    flags[((size_t)b * 32 + qt) * 16 + kt] = all;
  }
}

// ---------------- kernel 2: QKV GEMM  C = A @ W^T + bias  (128x128 tiles) ----
// modes: 0 -> Q (scale log2e/8, bf16 [b,h,s,d]); 1 -> K (bf16 [b,h,s,d]);
//        2 -> V^T (bf16 [b,h,d,s])
__global__ void __launch_bounds__(256, 2)
gemm_kernel(const __hip_bfloat16* __restrict__ A0, const __hip_bfloat16* __restrict__ A1,
            const __hip_bfloat16* __restrict__ A2,
            const __hip_bfloat16* __restrict__ W0, const __hip_bfloat16* __restrict__ W1,
            const __hip_bfloat16* __restrict__ W2,
            const float* __restrict__ b0, const float* __restrict__ b1,
            const float* __restrict__ b2,
            __hip_bfloat16* __restrict__ O0, __hip_bfloat16* __restrict__ O1,
            __hip_bfloat16* __restrict__ O2) {
  __shared__ __align__(16) __hip_bfloat16 As[128 * 32];
  __shared__ __align__(16) __hip_bfloat16 Bs[128 * 32];

  const int z = blockIdx.z;
  const __hip_bfloat16* A  = (z == 0) ? A0 : ((z == 1) ? A1 : A2);
  const __hip_bfloat16* W  = (z == 0) ? W0 : ((z == 1) ? W1 : W2);
  const float* bi          = (z == 0) ? b0 : ((z == 1) ? b1 : b2);
  __hip_bfloat16* O        = (z == 0) ? O0 : ((z == 1) ? O1 : O2);

  const int t = threadIdx.x;
  const int w = t >> 6, lane = t & 63, quad = lane >> 4, l15 = lane & 15;
  const int m0 = blockIdx.y * 128, n0 = blockIdx.x * 128;
  const int wr = w >> 1, wc = w & 1;

  f32x4 acc[4][4];
#pragma unroll
  for (int i = 0; i < 4; ++i)
#pragma unroll
    for (int j = 0; j < 4; ++j) acc[i][j] = (f32x4)0.0f;

  for (int k0 = 0; k0 < EMB; k0 += 32) {
    __syncthreads();
#pragma unroll
    for (int rnd = 0; rnd < 2; ++rnd) {
      int idx = rnd * 256 + t;
      gll16(A + (size_t)(m0 + (idx >> 2)) * EMB + k0 + ((idx & 3) << 3),
            &As[(rnd * 256 + (w << 6)) * 8]);
      gll16(W + (size_t)(n0 + (idx >> 2)) * EMB + k0 + ((idx & 3) << 3),
            &Bs[(rnd * 256 + (w << 6)) * 8]);
    }
    __syncthreads();

    bf16x8 af[4], bfr[4];
#pragma unroll
    for (int i = 0; i < 4; ++i)
      af[i] = *(const bf16x8*)&As[(wr * 64 + i * 16 + l15) * 32 + quad * 8];
#pragma unroll
    for (int j = 0; j < 4; ++j)
      bfr[j] = *(const bf16x8*)&Bs[(wc * 64 + j * 16 + l15) * 32 + quad * 8];
#pragma unroll
    for (int i = 0; i < 4; ++i)
#pragma unroll
      for (int j = 0; j < 4; ++j)
        acc[i][j] = __builtin_amdgcn_mfma_f32_16x16x32_bf16(af[i], bfr[j], acc[i][j], 0, 0, 0);
  }

#pragma unroll
  for (int j = 0; j < 4; ++j) {
    const int ng = n0 + wc * 64 + j * 16 + l15;
    const float bb = bi[ng];
    const int h = ng >> 6, d = ng & 63;
#pragma unroll
    for (int i = 0; i < 4; ++i) {
#pragma unroll
      for (int r = 0; r < 4; ++r) {
        const int mg = m0 + wr * 64 + i * 16 + quad * 4 + r;
        const int b = mg >> 11, s = mg & 2047;
        float v = acc[i][j][r] + bb;
        if (z == 0) {        // Q, pre-scaled by log2e/8 so flash can use raw exp2
          O[(((size_t)b * NHEAD + h) * S_LEN + s) * HDIM + d] =
              __float2bfloat16(v * (0.125f * 1.4426950408889634f));
        } else if (z == 1) { // K
          O[(((size_t)b * NHEAD + h) * S_LEN + s) * HDIM + d] = __float2bfloat16(v);
        } else {             // V^T
          O[(((size_t)b * NHEAD + h) * HDIM + d) * S_LEN + s] = __float2bfloat16(v);
        }
      }
    }
  }
}

// ---------------- kernel 4: output projection, 64x128 tiles, fp32 out -------
__global__ void __launch_bounds__(256, 2)
gemm_o_kernel(const __hip_bfloat16* __restrict__ A, const __hip_bfloat16* __restrict__ W,
              const float* __restrict__ bi, float* __restrict__ O) {
  __shared__ __align__(16) __hip_bfloat16 As[64 * 32];
  __shared__ __align__(16) __hip_bfloat16 Bs[128 * 32];
  const int t = threadIdx.x;
  const int w = t >> 6, lane = t & 63, quad = lane >> 4, l15 = lane & 15;
  const int m0 = blockIdx.y * 64, n0 = blockIdx.x * 128;
  const int wr = w >> 1, wc = w & 1;

  f32x4 acc[2][4];
#pragma unroll
  for (int i = 0; i < 2; ++i)
#pragma unroll
    for (int j = 0; j < 4; ++j) acc[i][j] = (f32x4)0.0f;

  for (int k0 = 0; k0 < EMB; k0 += 32) {
    __syncthreads();
    gll16(A + (size_t)(m0 + (t >> 2)) * EMB + k0 + ((t & 3) << 3), &As[(w << 6) * 8]);
#pragma unroll
    for (int rnd = 0; rnd < 2; ++rnd) {
      int idx = rnd * 256 + t;
      gll16(W + (size_t)(n0 + (idx >> 2)) * EMB + k0 + ((idx & 3) << 3),
            &Bs[(rnd * 256 + (w << 6)) * 8]);
    }
    __syncthreads();

    bf16x8 af[2], bfr[4];
#pragma unroll
    for (int i = 0; i < 2; ++i)
      af[i] = *(const bf16x8*)&As[(wr * 32 + i * 16 + l15) * 32 + quad * 8];
#pragma unroll
    for (int j = 0; j < 4; ++j)
      bfr[j] = *(const bf16x8*)&Bs[(wc * 64 + j * 16 + l15) * 32 + quad * 8];
#pragma unroll
    for (int i = 0; i < 2; ++i)
#pragma unroll
      for (int j = 0; j < 4; ++j)
        acc[i][j] = __builtin_amdgcn_mfma_f32_16x16x32_bf16(af[i], bfr[j], acc[i][j], 0, 0, 0);
  }

#pragma unroll
  for (int j = 0; j < 4; ++j) {
    const int ng = n0 + wc * 64 + j * 16 + l15;
    const float bb = bi[ng];
#pragma unroll
    for (int i = 0; i < 2; ++i) {
#pragma unroll
      for (int r = 0; r < 4; ++r) {
        const int mg = m0 + wr * 32 + i * 16 + quad * 4 + r;
        O[(size_t)mg * EMB + ng] = acc[i][j][r] + bb;
      }
    }
  }
}

// ---------------- kernel 3: flash attention -----------------------------------
// Ps unioned into KP (extra barrier between last Ks read and P overwrite);
// bias folded into 25-entry exp-multiplier table; log2e pre-folded into Q;
// staging addrs hoisted to 2 per-lane pointers with constant strides.
__global__ void __launch_bounds__(256, 4)
flash_kernel(const __hip_bfloat16* __restrict__ qws, const __hip_bfloat16* __restrict__ kws,
             const __hip_bfloat16* __restrict__ vtws, const int* __restrict__ responses,
             const int* __restrict__ mask, const float* __restrict__ Wm,
             const unsigned* __restrict__ flags, __hip_bfloat16* __restrict__ att) {
  __shared__ __align__(16) __hip_bfloat16 KP[128 * 64];  // K tile, then reused as P tile
  __shared__ __align__(16) __hip_bfloat16 Vs[64 * 128];  // [d][key], swizzled
  __shared__ unsigned char rb[S_LEN];                    // key responses as bytes
  __shared__ float tab[32];                              // exp bias multipliers [rq][rk]

  const int t = threadIdx.x;
  const int w = t >> 6, lane = t & 63, quad = lane >> 4, l15 = lane & 15;
  const int qt = blockIdx.x, h = blockIdx.y, b = blockIdx.z;
  const int bh = b * NHEAD + h;
  const int q0 = qt * 64;

  // stage bias table + key responses (visible after first loop barrier)
  if (t < 25) {
    const float c = Wm[h] * (0.0625f * 1.4426950408889634f);  // Wm/16 * log2e
    const int rq = t / 5, rk = t % 5;
    tab[t] = __builtin_amdgcn_exp2f(c * (float)(2 * rq * rk - rk * rk));
  }
#pragma unroll
  for (int i = 0; i < 8; ++i)
    rb[i * 256 + t] = (unsigned char)responses[b * S_LEN + i * 256 + t];

  // Q fragments (A-layout), in registers for the whole kernel
  const __hip_bfloat16* qbase = qws + ((size_t)bh * S_LEN + q0) * HDIM;
  bf16x8 qf[2];
#pragma unroll
  for (int ks = 0; ks < 2; ++ks)
    qf[ks] = *(const bf16x8*)(qbase + (size_t)(w * 16 + l15) * HDIM + ks * 32 + quad * 8);

  int toff[4];  // tab row offset for this lane's 4 q rows
#pragma unroll
  for (int r = 0; r < 4; ++r)
    toff[r] = responses[b * S_LEN + q0 + w * 16 + quad * 4 + r] * 5;

  // hoisted staging source pointers (p-offsets proven lane-invariant)
  const __hip_bfloat16* kptr = kws + ((size_t)bh * S_LEN + (t >> 3)) * HDIM +
                               (((t & 7) ^ ((t >> 3) & 7)) << 3);
  const __hip_bfloat16* vptr = vtws + ((size_t)bh * HDIM + (t >> 4)) * S_LEN +
                               (((t & 15) ^ ((t >> 4) & 7)) << 3);

  float lsum[4] = {0.f, 0.f, 0.f, 0.f};
  f32x4 acc_o[4];
#pragma unroll
  for (int dt = 0; dt < 4; ++dt) acc_o[dt] = (f32x4)0.0f;

  for (int kt = 0; kt < S_LEN / 128; ++kt) {
    __syncthreads();  // A: staging may overwrite KP(=P) and Vs
#pragma unroll
    for (int p = 0; p < 4; ++p) {
      gll16(kptr + p * 32 * HDIM,  &KP[(p * 256 + (w << 6)) * 8]);
      gll16(vptr + p * 16 * S_LEN, &Vs[(p * 256 + (w << 6)) * 8]);
    }
    kptr += 128 * HDIM;
    vptr += 128;
    __syncthreads();  // B: staging complete

    // QK^T: 16 q rows x 128 keys per wave
    f32x4 sc[8];
#pragma unroll
    for (int ct = 0; ct < 8; ++ct) {
      const int rowk = ct * 16 + l15;
      bf16x8 kf0 = *(const bf16x8*)&KP[rowk * 64 + (((0 + quad) ^ (l15 & 7)) << 3)];
      bf16x8 kf1 = *(const bf16x8*)&KP[rowk * 64 + (((4 + quad) ^ (l15 & 7)) << 3)];
      sc[ct] = __builtin_amdgcn_mfma_f32_16x16x32_bf16(qf[0], kf0, (f32x4)0.0f, 0, 0, 0);
      sc[ct] = __builtin_amdgcn_mfma_f32_16x16x32_bf16(qf[1], kf1, sc[ct], 0, 0, 0);
    }

    // prefetch key responses for this tile (rb region is never overwritten)
    int rk8[8];
#pragma unroll
    for (int ct = 0; ct < 8; ++ct) rk8[ct] = rb[kt * 128 + ct * 16 + l15];

    const unsigned fl = flags[((size_t)b * 32 + qt) * 16 + kt];

    __syncthreads();  // C: all waves done reading K from KP; safe to write P

    // softmax (no max subtraction: scores bounded); P -> KP in A-layout bands
#pragma unroll
    for (int ct = 0; ct < 8; ++ct) {
      const int cb = (ct << 1) | (l15 >> 3);
#pragma unroll
      for (int r = 0; r < 4; ++r) {
        float p = __builtin_amdgcn_exp2f(sc[ct][r]) * tab[toff[r] + rk8[ct]];
        if (!fl) {  // slow path: per-element mask (all-ones mask never takes it)
          int mq = mask[((size_t)b * S_LEN + q0 + w * 16 + quad * 4 + r) * S_LEN +
                        kt * 128 + ct * 16 + l15];
          p = mq ? p : 0.0f;
        }
        lsum[r] += p;
        const int prow = w * 16 + quad * 4 + r;
        KP[prow * 128 + ((cb ^ (prow & 7)) << 3) + (l15 & 7)] = __float2bfloat16(p);
      }
    }

    // PV: wave-private P band (written+read by same wave; no barrier needed)
#pragma unroll
    for (int kst = 0; kst < 4; ++kst) {
      const int prow = w * 16 + l15;
      bf16x8 pf = *(const bf16x8*)&KP[prow * 128 + ((((kst << 2) + quad) ^ (l15 & 7)) << 3)];
#pragma unroll
      for (int dt = 0; dt < 4; ++dt) {
        const int vrow = dt * 16 + l15;
        bf16x8 vf = *(const bf16x8*)&Vs[vrow * 128 + ((((kst << 2) + quad) ^ (l15 & 7)) << 3)];
        acc_o[dt] = __builtin_amdgcn_mfma_f32_16x16x32_bf16(pf, vf, acc_o[dt], 0, 0, 0);
      }
    }
  }

  // finalize: reduce lsum over the 16 lanes of each quad-row, normalize, store
#pragma unroll
  for (int r = 0; r < 4; ++r) {
#pragma unroll
    for (int off = 1; off < 16; off <<= 1) lsum[r] += __shfl_xor(lsum[r], off, 64);
    lsum[r] = 1.0f / lsum[r];
  }
#pragma unroll
  for (int dt = 0; dt < 4; ++dt) {
#pragma unroll
    for (int r = 0; r < 4; ++r) {
      float v = acc_o[dt][r] * lsum[r];
      att[((size_t)b * S_LEN + q0 + w * 16 + quad * 4 + r) * EMB + h * HDIM + dt * 16 + l15] =
          __float2bfloat16(v);
    }
  }
}

// ---------------------------------------------------------------------------
extern "C" void kernel_launch(void* const* d_in, const int* in_sizes, int n_in,
                              void* d_out, int out_size, void* d_ws, size_t ws_size,
                              hipStream_t stream) {
  const float* query = (const float*)d_in[0];
  const float* key_  = (const float*)d_in[1];
  const float* value = (const float*)d_in[2];
  const int* responses = (const int*)d_in[3];
  const int* mask      = (const int*)d_in[4];
  const float* Wq = (const float*)d_in[5];
  const float* bq = (const float*)d_in[6];
  const float* Wk = (const float*)d_in[7];
  const float* bk = (const float*)d_in[8];
  const float* Wv = (const float*)d_in[9];
  const float* bv = (const float*)d_in[10];
  const float* Wo = (const float*)d_in[11];
  const float* bo = (const float*)d_in[12];
  const float* Wm = (const float*)d_in[13];
  // d_in[14] (bm): per-row constant under softmax -> exactly cancels; unused.

  __hip_bfloat16* ws = (__hip_bfloat16*)d_ws;
  const size_t NTOK = (size_t)BATCH * S_LEN * EMB;  // 4 Mi elements
  const size_t NW   = (size_t)EMB * EMB;            // 1 Mi elements
  __hip_bfloat16* qcast = ws;
  __hip_bfloat16* kcast = ws + NTOK;
  __hip_bfloat16* vcast = ws + 2 * NTOK;
  __hip_bfloat16* wqb   = ws + 3 * NTOK;
  __hip_bfloat16* wkb   = wqb + NW;
  __hip_bfloat16* wvb   = wqb + 2 * NW;
  __hip_bfloat16* wob   = wqb + 3 * NW;
  __hip_bfloat16* qws   = wqb + 4 * NW;
  __hip_bfloat16* kws   = qws + NTOK;
  __hip_bfloat16* vtws  = qws + 2 * NTOK;
  __hip_bfloat16* att   = qws + 3 * NTOK;
  unsigned* flags       = (unsigned*)(qws + 4 * NTOK);
  float* out            = (float*)d_out;

  cast_kernel<<<dim3(1024, 7), 256, 0, stream>>>(query, key_, value, Wq, Wk, Wv, Wo,
                                                 qcast, kcast, vcast, wqb, wkb, wvb, wob);
  mask_flags_kernel<<<dim3(16, 32, 2), 256, 0, stream>>>(mask, flags);
  gemm_kernel<<<dim3(8, 32, 3), 256, 0, stream>>>(qcast, kcast, vcast, wqb, wkb, wvb,
                                                  bq, bk, bv, qws, kws, vtws);
  flash_kernel<<<dim3(32, 16, 2), 256, 0, stream>>>(qws, kws, vtws, responses, mask,
                                                    Wm, flags, att);
  gemm_o_kernel<<<dim3(8, 64), 256, 0, stream>>>(att, wob, bo, out);
}

// Round 4
// 262.947 us; speedup vs baseline: 1.2574x; 1.1225x over previous
//
#include <hip/hip_runtime.h>
#include <hip/hip_bf16.h>
#include <stdint.h>

#define S_LEN 2048
#define EMB   1024
#define NHEAD 16
#define HDIM  64
#define BATCH 2

typedef __bf16 bf16x8 __attribute__((ext_vector_type(8)));
typedef float  f32x4  __attribute__((ext_vector_type(4)));

// async global->LDS, 16B per lane; LDS dest = wave-uniform base + lane*16
__device__ __forceinline__ void gll16(const void* g, void* l) {
  __builtin_amdgcn_global_load_lds(
      (const __attribute__((address_space(1))) void*)g,
      (__attribute__((address_space(3))) void*)l,
      16, 0, 0);
}

// ---------------- kernel 0: fused fp32->bf16 cast + mask tile flags ----------
__global__ void __launch_bounds__(256) cast_mask_kernel(
    const float* __restrict__ s0, const float* __restrict__ s1, const float* __restrict__ s2,
    const float* __restrict__ s3, const float* __restrict__ s4, const float* __restrict__ s5,
    const float* __restrict__ s6,
    __hip_bfloat16* __restrict__ d0, __hip_bfloat16* __restrict__ d1,
    __hip_bfloat16* __restrict__ d2, __hip_bfloat16* __restrict__ d3,
    __hip_bfloat16* __restrict__ d4, __hip_bfloat16* __restrict__ d5,
    __hip_bfloat16* __restrict__ d6,
    const int* __restrict__ mask, unsigned* __restrict__ flags) {
  const int z = blockIdx.y;
  const int t = threadIdx.x;
  if (z == 7) {  // mask tile flags: 64q x 128k tiles
    const int kt = blockIdx.x & 15, qt = (blockIdx.x >> 4) & 31, b = (int)blockIdx.x >> 9;
    const int* base = mask + ((size_t)b * S_LEN + (size_t)qt * 64) * S_LEN + (size_t)kt * 128;
    int ok = 1;
#pragma unroll
    for (int p = 0; p < 8; ++p) {
      int idx = p * 256 + t;
      int row = idx >> 5, c4 = idx & 31;
      const int4 v = *(const int4*)(base + (size_t)row * S_LEN + c4 * 4);
      ok &= (v.x != 0) & (v.y != 0) & (v.z != 0) & (v.w != 0);
    }
    unsigned long long bl = __ballot(ok);
    __shared__ unsigned long long bw[4];
    bw[t >> 6] = bl;
    __syncthreads();
    if (t == 0) {
      unsigned all = ((bw[0] & bw[1] & bw[2] & bw[3]) == ~0ull) ? 1u : 0u;
      flags[((size_t)b * 32 + qt) * 16 + kt] = all;
    }
    return;
  }
  const float* s = (z == 0) ? s0 : (z == 1) ? s1 : (z == 2) ? s2 : (z == 3) ? s3
                 : (z == 4) ? s4 : (z == 5) ? s5 : s6;
  __hip_bfloat16* d = (z == 0) ? d0 : (z == 1) ? d1 : (z == 2) ? d2 : (z == 3) ? d3
                    : (z == 4) ? d4 : (z == 5) ? d5 : d6;
  const int n = (z < 3) ? (BATCH * S_LEN * EMB) : (EMB * EMB);
  const size_t i = ((size_t)blockIdx.x * 256 + t) * 16;
  if (i >= (size_t)n) return;
  __hip_bfloat16 tmp[16];
#pragma unroll
  for (int j = 0; j < 4; ++j) {
    const float4 v = *(const float4*)(s + i + j * 4);
    tmp[j * 4 + 0] = __float2bfloat16(v.x);
    tmp[j * 4 + 1] = __float2bfloat16(v.y);
    tmp[j * 4 + 2] = __float2bfloat16(v.z);
    tmp[j * 4 + 3] = __float2bfloat16(v.w);
  }
  *(bf16x8*)(d + i)     = *(bf16x8*)&tmp[0];
  *(bf16x8*)(d + i + 8) = *(bf16x8*)&tmp[8];
}

// ---------------- kernel 1: QKV GEMM  C = A @ W^T + bias  (128x128 tiles) ----
// z=0 -> Q (scale log2e/8, [b,h,s,d]); z=1 -> K ([b,h,s,d]);
// z=2 -> V frag-packed: idx = bh*131072 + (s>>7)*8192
//        + ((((s>>5)&3)*4 + ((s>>2)&3))*64 + d)*8 + ((s>>4)&1)*4 + (s&3)
__global__ void __launch_bounds__(256, 2)
gemm_kernel(const __hip_bfloat16* __restrict__ A0, const __hip_bfloat16* __restrict__ A1,
            const __hip_bfloat16* __restrict__ A2,
            const __hip_bfloat16* __restrict__ W0, const __hip_bfloat16* __restrict__ W1,
            const __hip_bfloat16* __restrict__ W2,
            const float* __restrict__ b0, const float* __restrict__ b1,
            const float* __restrict__ b2,
            __hip_bfloat16* __restrict__ O0, __hip_bfloat16* __restrict__ O1,
            __hip_bfloat16* __restrict__ O2) {
  __shared__ __align__(16) __hip_bfloat16 As[128 * 32];
  __shared__ __align__(16) __hip_bfloat16 Bs[128 * 32];

  const int z = blockIdx.z;
  const __hip_bfloat16* A  = (z == 0) ? A0 : ((z == 1) ? A1 : A2);
  const __hip_bfloat16* W  = (z == 0) ? W0 : ((z == 1) ? W1 : W2);
  const float* bi          = (z == 0) ? b0 : ((z == 1) ? b1 : b2);
  __hip_bfloat16* O        = (z == 0) ? O0 : ((z == 1) ? O1 : O2);

  const int t = threadIdx.x;
  const int w = t >> 6, lane = t & 63, quad = lane >> 4, l15 = lane & 15;
  const int m0 = blockIdx.y * 128, n0 = blockIdx.x * 128;
  const int wr = w >> 1, wc = w & 1;

  f32x4 acc[4][4];
#pragma unroll
  for (int i = 0; i < 4; ++i)
#pragma unroll
    for (int j = 0; j < 4; ++j) acc[i][j] = (f32x4)0.0f;

  for (int k0 = 0; k0 < EMB; k0 += 32) {
    __syncthreads();
#pragma unroll
    for (int rnd = 0; rnd < 2; ++rnd) {
      int idx = rnd * 256 + t;
      gll16(A + (size_t)(m0 + (idx >> 2)) * EMB + k0 + ((idx & 3) << 3),
            &As[(rnd * 256 + (w << 6)) * 8]);
      gll16(W + (size_t)(n0 + (idx >> 2)) * EMB + k0 + ((idx & 3) << 3),
            &Bs[(rnd * 256 + (w << 6)) * 8]);
    }
    __syncthreads();

    bf16x8 af[4], bfr[4];
#pragma unroll
    for (int i = 0; i < 4; ++i)
      af[i] = *(const bf16x8*)&As[(wr * 64 + i * 16 + l15) * 32 + quad * 8];
#pragma unroll
    for (int j = 0; j < 4; ++j)
      bfr[j] = *(const bf16x8*)&Bs[(wc * 64 + j * 16 + l15) * 32 + quad * 8];
#pragma unroll
    for (int i = 0; i < 4; ++i)
#pragma unroll
      for (int j = 0; j < 4; ++j)
        acc[i][j] = __builtin_amdgcn_mfma_f32_16x16x32_bf16(af[i], bfr[j], acc[i][j], 0, 0, 0);
  }

#pragma unroll
  for (int j = 0; j < 4; ++j) {
    const int ng = n0 + wc * 64 + j * 16 + l15;
    const float bb = bi[ng];
    const int h = ng >> 6, d = ng & 63;
#pragma unroll
    for (int i = 0; i < 4; ++i) {
#pragma unroll
      for (int r = 0; r < 4; ++r) {
        const int mg = m0 + wr * 64 + i * 16 + quad * 4 + r;
        const int b = mg >> 11, s = mg & 2047;
        float v = acc[i][j][r] + bb;
        if (z == 0) {        // Q, pre-scaled by log2e/8 so flash uses raw exp2
          O[(((size_t)b * NHEAD + h) * S_LEN + s) * HDIM + d] =
              __float2bfloat16(v * (0.125f * 1.4426950408889634f));
        } else if (z == 1) { // K
          O[(((size_t)b * NHEAD + h) * S_LEN + s) * HDIM + d] = __float2bfloat16(v);
        } else {             // V frag-packed (matches flash PV B-operand layout)
          const size_t idx = (size_t)(b * NHEAD + h) * 131072 + (size_t)(s >> 7) * 8192 +
                             (size_t)((((s >> 5) & 3) * 4 + ((s >> 2) & 3)) * 64 + d) * 8 +
                             ((s >> 4) & 1) * 4 + (s & 3);
          O[idx] = __float2bfloat16(v);
        }
      }
    }
  }
}

// ---------------- kernel 3: output projection, 64x128 tiles, fp32 out -------
__global__ void __launch_bounds__(256, 2)
gemm_o_kernel(const __hip_bfloat16* __restrict__ A, const __hip_bfloat16* __restrict__ W,
              const float* __restrict__ bi, float* __restrict__ O) {
  __shared__ __align__(16) __hip_bfloat16 As[64 * 32];
  __shared__ __align__(16) __hip_bfloat16 Bs[128 * 32];
  const int t = threadIdx.x;
  const int w = t >> 6, lane = t & 63, quad = lane >> 4, l15 = lane & 15;
  const int m0 = blockIdx.y * 64, n0 = blockIdx.x * 128;
  const int wr = w >> 1, wc = w & 1;

  f32x4 acc[2][4];
#pragma unroll
  for (int i = 0; i < 2; ++i)
#pragma unroll
    for (int j = 0; j < 4; ++j) acc[i][j] = (f32x4)0.0f;

  for (int k0 = 0; k0 < EMB; k0 += 32) {
    __syncthreads();
    gll16(A + (size_t)(m0 + (t >> 2)) * EMB + k0 + ((t & 3) << 3), &As[(w << 6) * 8]);
#pragma unroll
    for (int rnd = 0; rnd < 2; ++rnd) {
      int idx = rnd * 256 + t;
      gll16(W + (size_t)(n0 + (idx >> 2)) * EMB + k0 + ((idx & 3) << 3),
            &Bs[(rnd * 256 + (w << 6)) * 8]);
    }
    __syncthreads();

    bf16x8 af[2], bfr[4];
#pragma unroll
    for (int i = 0; i < 2; ++i)
      af[i] = *(const bf16x8*)&As[(wr * 32 + i * 16 + l15) * 32 + quad * 8];
#pragma unroll
    for (int j = 0; j < 4; ++j)
      bfr[j] = *(const bf16x8*)&Bs[(wc * 64 + j * 16 + l15) * 32 + quad * 8];
#pragma unroll
    for (int i = 0; i < 2; ++i)
#pragma unroll
      for (int j = 0; j < 4; ++j)
        acc[i][j] = __builtin_amdgcn_mfma_f32_16x16x32_bf16(af[i], bfr[j], acc[i][j], 0, 0, 0);
  }

#pragma unroll
  for (int j = 0; j < 4; ++j) {
    const int ng = n0 + wc * 64 + j * 16 + l15;
    const float bb = bi[ng];
#pragma unroll
    for (int i = 0; i < 2; ++i) {
#pragma unroll
      for (int r = 0; r < 4; ++r) {
        const int mg = m0 + wr * 32 + i * 16 + quad * 4 + r;
        O[(size_t)mg * EMB + ng] = acc[i][j][r] + bb;
      }
    }
  }
}

// ---------------- kernel 2: flash attention, register-resident P ------------
// QK^T computed TRANSPOSED (operands swapped): lane holds scores for ONE q
// (=l15) and keys quad*4+r. That C-layout == A-operand layout of a K-chunked
// PV MFMA: two 16-key groups pack into one bf16x8 A-frag for 16x16x32 (k-slot
// relabeling is valid because V is staged in matching frag-packed order).
// P never touches LDS; bias tab replaced by 4 VALU ops (rq is lane-constant).
__global__ void __launch_bounds__(256, 4)
flash_kernel(const __hip_bfloat16* __restrict__ qws, const __hip_bfloat16* __restrict__ kws,
             const __hip_bfloat16* __restrict__ vpk, const int* __restrict__ responses,
             const int* __restrict__ mask, const float* __restrict__ Wm,
             const unsigned* __restrict__ flags, __hip_bfloat16* __restrict__ att) {
  __shared__ __align__(16) __hip_bfloat16 Ks[128 * 64];  // [key][d], XOR-swizzled
  __shared__ __align__(16) __hip_bfloat16 Vs[8192];      // frag-packed V tile (16 KB)
  __shared__ unsigned char rb[S_LEN];                    // key responses as bytes

  const int t = threadIdx.x;
  const int w = t >> 6, lane = t & 63, quad = lane >> 4, l15 = lane & 15;
  const int qt = blockIdx.x, h = blockIdx.y, b = blockIdx.z;
  const int bh = b * NHEAD + h;
  const int q0 = qt * 64;

  // stage key responses as bytes (read after first barrier B)
#pragma unroll
  for (int i = 0; i < 8; ++i)
    rb[i * 256 + t] = (unsigned char)responses[b * S_LEN + i * 256 + t];

  // Q fragments: this wave's q rows live on l15 (B-operand: n=l15 -> q)
  const __hip_bfloat16* qbase = qws + ((size_t)bh * S_LEN + q0) * HDIM;
  bf16x8 qf[2];
#pragma unroll
  for (int ks = 0; ks < 2; ++ks)
    qf[ks] = *(const bf16x8*)(qbase + (size_t)(w * 16 + l15) * HDIM + ks * 32 + quad * 8);

  const float c = Wm[h] * (0.0625f * 1.4426950408889634f);  // Wm/16 * log2e
  const float rqf = (float)responses[b * S_LEN + q0 + w * 16 + l15];
  const float A2 = 2.0f * c * rqf;

  // hoisted staging source pointers
  const __hip_bfloat16* kptr = kws + ((size_t)bh * S_LEN + (t >> 3)) * HDIM +
                               (((t & 7) ^ ((t >> 3) & 7)) << 3);
  const __hip_bfloat16* vptr = vpk + (size_t)bh * 131072 + (size_t)t * 8;

  float lsum = 0.0f;
  f32x4 acc_o[4];
#pragma unroll
  for (int dt = 0; dt < 4; ++dt) acc_o[dt] = (f32x4)0.0f;

  for (int kt = 0; kt < S_LEN / 128; ++kt) {
    __syncthreads();  // A: prior PV/QK reads of Ks/Vs complete
#pragma unroll
    for (int p = 0; p < 4; ++p) {
      gll16(kptr + p * 32 * HDIM, &Ks[(p * 256 + (w << 6)) * 8]);
      gll16(vptr + p * 2048,      &Vs[(p * 256 + (w << 6)) * 8]);
    }
    kptr += 128 * HDIM;
    vptr += 8192;
    __syncthreads();  // B: staging complete

    const unsigned fl = flags[((size_t)b * 32 + qt) * 16 + kt];

    bf16x8 pfr[4];  // packed P A-frags, one per 32-key pair-group
#pragma unroll
    for (int ct = 0; ct < 8; ++ct) {
      // S^T tile: a=K rows (m=key), b=Q rows (n=q)
      const int rowk = ct * 16 + l15;
      bf16x8 kf0 = *(const bf16x8*)&Ks[rowk * 64 + ((quad ^ (l15 & 7)) << 3)];
      bf16x8 kf1 = *(const bf16x8*)&Ks[rowk * 64 + (((4 + quad) ^ (l15 & 7)) << 3)];
      f32x4 sc = __builtin_amdgcn_mfma_f32_16x16x32_bf16(kf0, qf[0], (f32x4)0.0f, 0, 0, 0);
      sc = __builtin_amdgcn_mfma_f32_16x16x32_bf16(kf1, qf[1], sc, 0, 0, 0);

      const unsigned ru = *(const unsigned*)&rb[kt * 128 + ct * 16 + quad * 4];

      __hip_bfloat16 pb[4];
#pragma unroll
      for (int r = 0; r < 4; ++r) {
        const float rkf = (float)((ru >> (8 * r)) & 255u);
        const float tt = fmaf(-c, rkf, A2);          // 2c*rq - c*rk
        const float sb = fmaf(rkf, tt, sc[r]);       // score + c*rk*(2rq-rk)
        float p = __builtin_amdgcn_exp2f(sb);
        if (!fl) {  // slow path: per-element mask (all-ones mask never takes it)
          int mq = mask[((size_t)b * S_LEN + q0 + w * 16 + l15) * S_LEN +
                        kt * 128 + ct * 16 + quad * 4 + r];
          p = mq ? p : 0.0f;
        }
        lsum += p;
        pb[r] = __float2bfloat16(p);
      }
      __hip_bfloat16* half = (__hip_bfloat16*)&pfr[ct >> 1] + (ct & 1) * 4;
      half[0] = pb[0]; half[1] = pb[1]; half[2] = pb[2]; half[3] = pb[3];
    }

    // PV: one K=32 MFMA covers a 32-key pair-group; V frag read matches layout
#pragma unroll
    for (int ct2 = 0; ct2 < 4; ++ct2) {
#pragma unroll
      for (int dt = 0; dt < 4; ++dt) {
        bf16x8 vv = *(const bf16x8*)&Vs[((((ct2 << 2) + quad) << 6) + (dt << 4) + l15) << 3];
        acc_o[dt] = __builtin_amdgcn_mfma_f32_16x16x32_bf16(pfr[ct2], vv, acc_o[dt], 0, 0, 0);
      }
    }
  }

  // lsum lives per lane for q=l15; reduce across the 4 quads
  lsum += __shfl_xor(lsum, 16, 64);
  lsum += __shfl_xor(lsum, 32, 64);
  // output rows are q=quad*4+r: pull matching 1/lsum via shuffle
  float inv[4];
#pragma unroll
  for (int r = 0; r < 4; ++r) inv[r] = 1.0f / __shfl(lsum, quad * 4 + r, 64);

#pragma unroll
  for (int dt = 0; dt < 4; ++dt) {
#pragma unroll
    for (int r = 0; r < 4; ++r) {
      float v = acc_o[dt][r] * inv[r];
      att[((size_t)b * S_LEN + q0 + w * 16 + quad * 4 + r) * EMB + h * HDIM + dt * 16 + l15] =
          __float2bfloat16(v);
    }
  }
}

// ---------------------------------------------------------------------------
extern "C" void kernel_launch(void* const* d_in, const int* in_sizes, int n_in,
                              void* d_out, int out_size, void* d_ws, size_t ws_size,
                              hipStream_t stream) {
  const float* query = (const float*)d_in[0];
  const float* key_  = (const float*)d_in[1];
  const float* value = (const float*)d_in[2];
  const int* responses = (const int*)d_in[3];
  const int* mask      = (const int*)d_in[4];
  const float* Wq = (const float*)d_in[5];
  const float* bq = (const float*)d_in[6];
  const float* Wk = (const float*)d_in[7];
  const float* bk = (const float*)d_in[8];
  const float* Wv = (const float*)d_in[9];
  const float* bv = (const float*)d_in[10];
  const float* Wo = (const float*)d_in[11];
  const float* bo = (const float*)d_in[12];
  const float* Wm = (const float*)d_in[13];
  // d_in[14] (bm): per-row constant under softmax -> exactly cancels; unused.

  __hip_bfloat16* ws = (__hip_bfloat16*)d_ws;
  const size_t NTOK = (size_t)BATCH * S_LEN * EMB;  // 4 Mi elements
  const size_t NW   = (size_t)EMB * EMB;            // 1 Mi elements
  __hip_bfloat16* qcast = ws;
  __hip_bfloat16* kcast = ws + NTOK;
  __hip_bfloat16* vcast = ws + 2 * NTOK;
  __hip_bfloat16* wqb   = ws + 3 * NTOK;
  __hip_bfloat16* wkb   = wqb + NW;
  __hip_bfloat16* wvb   = wqb + 2 * NW;
  __hip_bfloat16* wob   = wqb + 3 * NW;
  __hip_bfloat16* qws   = wqb + 4 * NW;
  __hip_bfloat16* kws   = qws + NTOK;
  __hip_bfloat16* vpk   = qws + 2 * NTOK;
  __hip_bfloat16* att   = qws + 3 * NTOK;
  unsigned* flags       = (unsigned*)(qws + 4 * NTOK);
  float* out            = (float*)d_out;

  cast_mask_kernel<<<dim3(1024, 8), 256, 0, stream>>>(
      query, key_, value, Wq, Wk, Wv, Wo,
      qcast, kcast, vcast, wqb, wkb, wvb, wob, mask, flags);
  gemm_kernel<<<dim3(8, 32, 3), 256, 0, stream>>>(qcast, kcast, vcast, wqb, wkb, wvb,
                                                  bq, bk, bv, qws, kws, vpk);
  flash_kernel<<<dim3(32, 16, 2), 256, 0, stream>>>(qws, kws, vpk, responses, mask,
                                                    Wm, flags, att);
  gemm_o_kernel<<<dim3(8, 64), 256, 0, stream>>>(att, wob, bo, out);
}

// Round 5
// 254.809 us; speedup vs baseline: 1.2975x; 1.0319x over previous
//
#include <hip/hip_runtime.h>
#include <hip/hip_bf16.h>
#include <stdint.h>

#define S_LEN 2048
#define EMB   1024
#define NHEAD 16
#define HDIM  64
#define BATCH 2

typedef __bf16 bf16x8 __attribute__((ext_vector_type(8)));
typedef float  f32x4  __attribute__((ext_vector_type(4)));

// async global->LDS, 16B per lane; LDS dest = wave-uniform base + lane*16
__device__ __forceinline__ void gll16(const void* g, void* l) {
  __builtin_amdgcn_global_load_lds(
      (const __attribute__((address_space(1))) void*)g,
      (__attribute__((address_space(3))) void*)l,
      16, 0, 0);
}

// ---------------- kernel 0: fused fp32->bf16 cast + mask tile flags ----------
__global__ void __launch_bounds__(256) cast_mask_kernel(
    const float* __restrict__ s0, const float* __restrict__ s1, const float* __restrict__ s2,
    const float* __restrict__ s3, const float* __restrict__ s4, const float* __restrict__ s5,
    const float* __restrict__ s6,
    __hip_bfloat16* __restrict__ d0, __hip_bfloat16* __restrict__ d1,
    __hip_bfloat16* __restrict__ d2, __hip_bfloat16* __restrict__ d3,
    __hip_bfloat16* __restrict__ d4, __hip_bfloat16* __restrict__ d5,
    __hip_bfloat16* __restrict__ d6,
    const int* __restrict__ mask, unsigned* __restrict__ flags) {
  const int z = blockIdx.y;
  const int t = threadIdx.x;
  if (z == 7) {  // mask tile flags: 64q x 128k tiles
    const int kt = blockIdx.x & 15, qt = (blockIdx.x >> 4) & 31, b = (int)blockIdx.x >> 9;
    const int* base = mask + ((size_t)b * S_LEN + (size_t)qt * 64) * S_LEN + (size_t)kt * 128;
    int ok = 1;
#pragma unroll
    for (int p = 0; p < 8; ++p) {
      int idx = p * 256 + t;
      int row = idx >> 5, c4 = idx & 31;
      const int4 v = *(const int4*)(base + (size_t)row * S_LEN + c4 * 4);
      ok &= (v.x != 0) & (v.y != 0) & (v.z != 0) & (v.w != 0);
    }
    unsigned long long bl = __ballot(ok);
    __shared__ unsigned long long bw[4];
    bw[t >> 6] = bl;
    __syncthreads();
    if (t == 0) {
      unsigned all = ((bw[0] & bw[1] & bw[2] & bw[3]) == ~0ull) ? 1u : 0u;
      flags[((size_t)b * 32 + qt) * 16 + kt] = all;
    }
    return;
  }
  const float* s = (z == 0) ? s0 : (z == 1) ? s1 : (z == 2) ? s2 : (z == 3) ? s3
                 : (z == 4) ? s4 : (z == 5) ? s5 : s6;
  __hip_bfloat16* d = (z == 0) ? d0 : (z == 1) ? d1 : (z == 2) ? d2 : (z == 3) ? d3
                    : (z == 4) ? d4 : (z == 5) ? d5 : d6;
  const int n = (z < 3) ? (BATCH * S_LEN * EMB) : (EMB * EMB);
  const size_t i = ((size_t)blockIdx.x * 256 + t) * 16;
  if (i >= (size_t)n) return;
  __hip_bfloat16 tmp[16];
#pragma unroll
  for (int j = 0; j < 4; ++j) {
    const float4 v = *(const float4*)(s + i + j * 4);
    tmp[j * 4 + 0] = __float2bfloat16(v.x);
    tmp[j * 4 + 1] = __float2bfloat16(v.y);
    tmp[j * 4 + 2] = __float2bfloat16(v.z);
    tmp[j * 4 + 3] = __float2bfloat16(v.w);
  }
  *(bf16x8*)(d + i)     = *(bf16x8*)&tmp[0];
  *(bf16x8*)(d + i + 8) = *(bf16x8*)&tmp[8];
}

// ---------------- kernel 1: QKV GEMM, 128x128 tiles, BK=64, XOR-swizzled LDS -
// z=0 -> Q (scale log2e/8, [b,h,s,d]); z=1 -> K ([b,h,s,d]);
// z=2 -> V frag-packed (matches flash PV B-operand layout)
__global__ void __launch_bounds__(256, 2)
gemm_kernel(const __hip_bfloat16* __restrict__ A0, const __hip_bfloat16* __restrict__ A1,
            const __hip_bfloat16* __restrict__ A2,
            const __hip_bfloat16* __restrict__ W0, const __hip_bfloat16* __restrict__ W1,
            const __hip_bfloat16* __restrict__ W2,
            const float* __restrict__ b0, const float* __restrict__ b1,
            const float* __restrict__ b2,
            __hip_bfloat16* __restrict__ O0, __hip_bfloat16* __restrict__ O1,
            __hip_bfloat16* __restrict__ O2) {
  __shared__ __align__(16) __hip_bfloat16 As[128 * 64];  // [row][64], col-block j holds src j^(row&7)
  __shared__ __align__(16) __hip_bfloat16 Bs[128 * 64];

  const int z = blockIdx.z;
  const __hip_bfloat16* A  = (z == 0) ? A0 : ((z == 1) ? A1 : A2);
  const __hip_bfloat16* W  = (z == 0) ? W0 : ((z == 1) ? W1 : W2);
  const float* bi          = (z == 0) ? b0 : ((z == 1) ? b1 : b2);
  __hip_bfloat16* O        = (z == 0) ? O0 : ((z == 1) ? O1 : O2);

  const int t = threadIdx.x;
  const int w = t >> 6, lane = t & 63, quad = lane >> 4, l15 = lane & 15;
  const int m0 = blockIdx.y * 128, n0 = blockIdx.x * 128;
  const int wr = w >> 1, wc = w & 1;

  f32x4 acc[4][4];
#pragma unroll
  for (int i = 0; i < 4; ++i)
#pragma unroll
    for (int j = 0; j < 4; ++j) acc[i][j] = (f32x4)0.0f;

  // hoisted per-lane staging sources (col-block swizzle is rnd-invariant)
  const int srow = t >> 3;
  const int scb  = (t & 7) ^ (srow & 7);
  const __hip_bfloat16* Ap = A + (size_t)(m0 + srow) * EMB + (scb << 3);
  const __hip_bfloat16* Wp = W + (size_t)(n0 + srow) * EMB + (scb << 3);

  for (int k0 = 0; k0 < EMB; k0 += 64) {
    __syncthreads();
#pragma unroll
    for (int rnd = 0; rnd < 4; ++rnd) {
      gll16(Ap + (size_t)(rnd * 32) * EMB + k0, &As[(rnd * 256 + (w << 6)) * 8]);
      gll16(Wp + (size_t)(rnd * 32) * EMB + k0, &Bs[(rnd * 256 + (w << 6)) * 8]);
    }
    __syncthreads();

    bf16x8 af[4][2], bfr[4][2];
#pragma unroll
    for (int i = 0; i < 4; ++i) {
      const int ra = wr * 64 + i * 16 + l15;
#pragma unroll
      for (int hh = 0; hh < 2; ++hh)
        af[i][hh] = *(const bf16x8*)&As[ra * 64 + ((((hh << 2) + quad) ^ (l15 & 7)) << 3)];
    }
#pragma unroll
    for (int j = 0; j < 4; ++j) {
      const int rbw = wc * 64 + j * 16 + l15;
#pragma unroll
      for (int hh = 0; hh < 2; ++hh)
        bfr[j][hh] = *(const bf16x8*)&Bs[rbw * 64 + ((((hh << 2) + quad) ^ (l15 & 7)) << 3)];
    }
#pragma unroll
    for (int hh = 0; hh < 2; ++hh)
#pragma unroll
      for (int i = 0; i < 4; ++i)
#pragma unroll
        for (int j = 0; j < 4; ++j)
          acc[i][j] =
              __builtin_amdgcn_mfma_f32_16x16x32_bf16(af[i][hh], bfr[j][hh], acc[i][j], 0, 0, 0);
  }

#pragma unroll
  for (int j = 0; j < 4; ++j) {
    const int ng = n0 + wc * 64 + j * 16 + l15;
    const float bb = bi[ng];
    const int h = ng >> 6, d = ng & 63;
#pragma unroll
    for (int i = 0; i < 4; ++i) {
#pragma unroll
      for (int r = 0; r < 4; ++r) {
        const int mg = m0 + wr * 64 + i * 16 + quad * 4 + r;
        const int b = mg >> 11, s = mg & 2047;
        float v = acc[i][j][r] + bb;
        if (z == 0) {        // Q, pre-scaled by log2e/8 so flash uses raw exp2
          O[(((size_t)b * NHEAD + h) * S_LEN + s) * HDIM + d] =
              __float2bfloat16(v * (0.125f * 1.4426950408889634f));
        } else if (z == 1) { // K
          O[(((size_t)b * NHEAD + h) * S_LEN + s) * HDIM + d] = __float2bfloat16(v);
        } else {             // V frag-packed
          const size_t idx = (size_t)(b * NHEAD + h) * 131072 + (size_t)(s >> 7) * 8192 +
                             (size_t)((((s >> 5) & 3) * 4 + ((s >> 2) & 3)) * 64 + d) * 8 +
                             ((s >> 4) & 1) * 4 + (s & 3);
          O[idx] = __float2bfloat16(v);
        }
      }
    }
  }
}

// ---------------- kernel 3: output projection, 64x128 tiles, BK=64 ----------
__global__ void __launch_bounds__(256, 2)
gemm_o_kernel(const __hip_bfloat16* __restrict__ A, const __hip_bfloat16* __restrict__ W,
              const float* __restrict__ bi, float* __restrict__ O) {
  __shared__ __align__(16) __hip_bfloat16 As[64 * 64];
  __shared__ __align__(16) __hip_bfloat16 Bs[128 * 64];
  const int t = threadIdx.x;
  const int w = t >> 6, lane = t & 63, quad = lane >> 4, l15 = lane & 15;
  const int m0 = blockIdx.y * 64, n0 = blockIdx.x * 128;
  const int wr = w >> 1, wc = w & 1;

  f32x4 acc[2][4];
#pragma unroll
  for (int i = 0; i < 2; ++i)
#pragma unroll
    for (int j = 0; j < 4; ++j) acc[i][j] = (f32x4)0.0f;

  const int srow = t >> 3;
  const int scb  = (t & 7) ^ (srow & 7);
  const __hip_bfloat16* Ap = A + (size_t)(m0 + srow) * EMB + (scb << 3);
  const __hip_bfloat16* Wp = W + (size_t)(n0 + srow) * EMB + (scb << 3);

  for (int k0 = 0; k0 < EMB; k0 += 64) {
    __syncthreads();
#pragma unroll
    for (int rnd = 0; rnd < 2; ++rnd)
      gll16(Ap + (size_t)(rnd * 32) * EMB + k0, &As[(rnd * 256 + (w << 6)) * 8]);
#pragma unroll
    for (int rnd = 0; rnd < 4; ++rnd)
      gll16(Wp + (size_t)(rnd * 32) * EMB + k0, &Bs[(rnd * 256 + (w << 6)) * 8]);
    __syncthreads();

    bf16x8 af[2][2], bfr[4][2];
#pragma unroll
    for (int i = 0; i < 2; ++i) {
      const int ra = wr * 32 + i * 16 + l15;
#pragma unroll
      for (int hh = 0; hh < 2; ++hh)
        af[i][hh] = *(const bf16x8*)&As[ra * 64 + ((((hh << 2) + quad) ^ (l15 & 7)) << 3)];
    }
#pragma unroll
    for (int j = 0; j < 4; ++j) {
      const int rbw = wc * 64 + j * 16 + l15;
#pragma unroll
      for (int hh = 0; hh < 2; ++hh)
        bfr[j][hh] = *(const bf16x8*)&Bs[rbw * 64 + ((((hh << 2) + quad) ^ (l15 & 7)) << 3)];
    }
#pragma unroll
    for (int hh = 0; hh < 2; ++hh)
#pragma unroll
      for (int i = 0; i < 2; ++i)
#pragma unroll
        for (int j = 0; j < 4; ++j)
          acc[i][j] =
              __builtin_amdgcn_mfma_f32_16x16x32_bf16(af[i][hh], bfr[j][hh], acc[i][j], 0, 0, 0);
  }

#pragma unroll
  for (int j = 0; j < 4; ++j) {
    const int ng = n0 + wc * 64 + j * 16 + l15;
    const float bb = bi[ng];
#pragma unroll
    for (int i = 0; i < 2; ++i) {
#pragma unroll
      for (int r = 0; r < 4; ++r) {
        const int mg = m0 + wr * 32 + i * 16 + quad * 4 + r;
        O[(size_t)mg * EMB + ng] = acc[i][j][r] + bb;
      }
    }
  }
}

// ---------------- kernel 2: flash attention, 128 q/block (512 thr) ----------
// Register-resident P via transposed QK^T (S^T C-layout == PV A-operand layout).
// 128-q blocks halve K/V staging traffic and barrier count per unit of work.
__global__ void __launch_bounds__(512, 4)
flash_kernel(const __hip_bfloat16* __restrict__ qws, const __hip_bfloat16* __restrict__ kws,
             const __hip_bfloat16* __restrict__ vpk, const int* __restrict__ responses,
             const int* __restrict__ mask, const float* __restrict__ Wm,
             const unsigned* __restrict__ flags, __hip_bfloat16* __restrict__ att) {
  __shared__ __align__(16) __hip_bfloat16 Ks[128 * 64];  // [key][d], XOR-swizzled
  __shared__ __align__(16) __hip_bfloat16 Vs[8192];      // frag-packed V tile (16 KB)
  __shared__ unsigned char rb[S_LEN];                    // key responses as bytes

  const int t = threadIdx.x;
  const int w = t >> 6, lane = t & 63, quad = lane >> 4, l15 = lane & 15;
  const int qt = blockIdx.x, h = blockIdx.y, b = blockIdx.z;
  const int bh = b * NHEAD + h;
  const int q0 = qt * 128;

  // stage key responses as bytes (read after first barrier B)
#pragma unroll
  for (int i = 0; i < 4; ++i)
    rb[i * 512 + t] = (unsigned char)responses[b * S_LEN + i * 512 + t];

  // Q fragments: this wave's 16 q rows live on l15 (B-operand of S^T MFMA)
  const __hip_bfloat16* qbase = qws + ((size_t)bh * S_LEN + q0) * HDIM;
  bf16x8 qf[2];
#pragma unroll
  for (int ks = 0; ks < 2; ++ks)
    qf[ks] = *(const bf16x8*)(qbase + (size_t)(w * 16 + l15) * HDIM + ks * 32 + quad * 8);

  const float c = Wm[h] * (0.0625f * 1.4426950408889634f);  // Wm/16 * log2e
  const float rqf = (float)responses[b * S_LEN + q0 + w * 16 + l15];
  const float A2 = 2.0f * c * rqf;

  // hoisted staging source pointers
  const __hip_bfloat16* kptr = kws + ((size_t)bh * S_LEN + (t >> 3)) * HDIM +
                               (((t & 7) ^ ((t >> 3) & 7)) << 3);
  const __hip_bfloat16* vptr = vpk + (size_t)bh * 131072 + (size_t)t * 8;

  float lsum = 0.0f;
  f32x4 acc_o[4];
#pragma unroll
  for (int dt = 0; dt < 4; ++dt) acc_o[dt] = (f32x4)0.0f;

  for (int kt = 0; kt < S_LEN / 128; ++kt) {
    __syncthreads();  // A: prior QK/PV reads of Ks/Vs complete
#pragma unroll
    for (int p = 0; p < 2; ++p) {
      gll16(kptr + p * 64 * HDIM, &Ks[(p * 512 + (w << 6)) * 8]);
      gll16(vptr + p * 4096,      &Vs[(p * 512 + (w << 6)) * 8]);
    }
    kptr += 128 * HDIM;
    vptr += 8192;
    __syncthreads();  // B: staging complete

    const unsigned fl = flags[((size_t)b * 32 + 2 * qt) * 16 + kt] &
                        flags[((size_t)b * 32 + 2 * qt + 1) * 16 + kt];

    bf16x8 pfr[4];  // packed P A-frags, one per 32-key pair-group
#pragma unroll
    for (int ct = 0; ct < 8; ++ct) {
      // S^T tile: A-operand = K rows (m=key), B-operand = Q rows (n=q)
      const int rowk = ct * 16 + l15;
      bf16x8 kf0 = *(const bf16x8*)&Ks[rowk * 64 + ((quad ^ (l15 & 7)) << 3)];
      bf16x8 kf1 = *(const bf16x8*)&Ks[rowk * 64 + (((4 + quad) ^ (l15 & 7)) << 3)];
      f32x4 sc = __builtin_amdgcn_mfma_f32_16x16x32_bf16(kf0, qf[0], (f32x4)0.0f, 0, 0, 0);
      sc = __builtin_amdgcn_mfma_f32_16x16x32_bf16(kf1, qf[1], sc, 0, 0, 0);

      const unsigned ru = *(const unsigned*)&rb[kt * 128 + ct * 16 + quad * 4];

      __hip_bfloat16 pb[4];
#pragma unroll
      for (int r = 0; r < 4; ++r) {
        const float rkf = (float)((ru >> (8 * r)) & 255u);
        const float tt = fmaf(-c, rkf, A2);          // 2c*rq - c*rk
        const float sb = fmaf(rkf, tt, sc[r]);       // score + c*rk*(2rq-rk)
        float p = __builtin_amdgcn_exp2f(sb);
        if (!fl) {  // slow path: per-element mask (all-ones mask never takes it)
          int mq = mask[((size_t)b * S_LEN + q0 + w * 16 + l15) * S_LEN +
                        kt * 128 + ct * 16 + quad * 4 + r];
          p = mq ? p : 0.0f;
        }
        lsum += p;
        pb[r] = __float2bfloat16(p);
      }
      __hip_bfloat16* half = (__hip_bfloat16*)&pfr[ct >> 1] + (ct & 1) * 4;
      half[0] = pb[0]; half[1] = pb[1]; half[2] = pb[2]; half[3] = pb[3];
    }

    // PV: one K=32 MFMA covers a 32-key pair-group; V frag read matches layout
#pragma unroll
    for (int ct2 = 0; ct2 < 4; ++ct2) {
#pragma unroll
      for (int dt = 0; dt < 4; ++dt) {
        bf16x8 vv = *(const bf16x8*)&Vs[((((ct2 << 2) + quad) << 6) + (dt << 4) + l15) << 3];
        acc_o[dt] = __builtin_amdgcn_mfma_f32_16x16x32_bf16(pfr[ct2], vv, acc_o[dt], 0, 0, 0);
      }
    }
  }

  // lsum lives per lane for q=l15; reduce across the 4 quads
  lsum += __shfl_xor(lsum, 16, 64);
  lsum += __shfl_xor(lsum, 32, 64);
  // output rows are q=quad*4+r: pull matching 1/lsum via shuffle
  float inv[4];
#pragma unroll
  for (int r = 0; r < 4; ++r) inv[r] = 1.0f / __shfl(lsum, quad * 4 + r, 64);

#pragma unroll
  for (int dt = 0; dt < 4; ++dt) {
#pragma unroll
    for (int r = 0; r < 4; ++r) {
      float v = acc_o[dt][r] * inv[r];
      att[((size_t)b * S_LEN + q0 + w * 16 + quad * 4 + r) * EMB + h * HDIM + dt * 16 + l15] =
          __float2bfloat16(v);
    }
  }
}

// ---------------------------------------------------------------------------
extern "C" void kernel_launch(void* const* d_in, const int* in_sizes, int n_in,
                              void* d_out, int out_size, void* d_ws, size_t ws_size,
                              hipStream_t stream) {
  const float* query = (const float*)d_in[0];
  const float* key_  = (const float*)d_in[1];
  const float* value = (const float*)d_in[2];
  const int* responses = (const int*)d_in[3];
  const int* mask      = (const int*)d_in[4];
  const float* Wq = (const float*)d_in[5];
  const float* bq = (const float*)d_in[6];
  const float* Wk = (const float*)d_in[7];
  const float* bk = (const float*)d_in[8];
  const float* Wv = (const float*)d_in[9];
  const float* bv = (const float*)d_in[10];
  const float* Wo = (const float*)d_in[11];
  const float* bo = (const float*)d_in[12];
  const float* Wm = (const float*)d_in[13];
  // d_in[14] (bm): per-row constant under softmax -> exactly cancels; unused.

  __hip_bfloat16* ws = (__hip_bfloat16*)d_ws;
  const size_t NTOK = (size_t)BATCH * S_LEN * EMB;  // 4 Mi elements
  const size_t NW   = (size_t)EMB * EMB;            // 1 Mi elements
  __hip_bfloat16* qcast = ws;
  __hip_bfloat16* kcast = ws + NTOK;
  __hip_bfloat16* vcast = ws + 2 * NTOK;
  __hip_bfloat16* wqb   = ws + 3 * NTOK;
  __hip_bfloat16* wkb   = wqb + NW;
  __hip_bfloat16* wvb   = wqb + 2 * NW;
  __hip_bfloat16* wob   = wqb + 3 * NW;
  __hip_bfloat16* qws   = wqb + 4 * NW;
  __hip_bfloat16* kws   = qws + NTOK;
  __hip_bfloat16* vpk   = qws + 2 * NTOK;
  __hip_bfloat16* att   = qws + 3 * NTOK;
  unsigned* flags       = (unsigned*)(qws + 4 * NTOK);
  float* out            = (float*)d_out;

  cast_mask_kernel<<<dim3(1024, 8), 256, 0, stream>>>(
      query, key_, value, Wq, Wk, Wv, Wo,
      qcast, kcast, vcast, wqb, wkb, wvb, wob, mask, flags);
  gemm_kernel<<<dim3(8, 32, 3), 256, 0, stream>>>(qcast, kcast, vcast, wqb, wkb, wvb,
                                                  bq, bk, bv, qws, kws, vpk);
  flash_kernel<<<dim3(16, 16, 2), 512, 0, stream>>>(qws, kws, vpk, responses, mask,
                                                    Wm, flags, att);
  gemm_o_kernel<<<dim3(8, 64), 256, 0, stream>>>(att, wob, bo, out);
}

// Round 6
// 249.556 us; speedup vs baseline: 1.3249x; 1.0211x over previous
//
#include <hip/hip_runtime.h>
#include <hip/hip_bf16.h>
#include <stdint.h>

#define S_LEN 2048
#define EMB   1024
#define NHEAD 16
#define HDIM  64
#define BATCH 2

typedef __bf16 bf16x8 __attribute__((ext_vector_type(8)));
typedef float  f32x4  __attribute__((ext_vector_type(4)));

// async global->LDS, 16B per lane; LDS dest = wave-uniform base + lane*16
__device__ __forceinline__ void gll16(const void* g, void* l) {
  __builtin_amdgcn_global_load_lds(
      (const __attribute__((address_space(1))) void*)g,
      (__attribute__((address_space(3))) void*)l,
      16, 0, 0);
}

// ---------------- kernel 0: fused fp32->bf16 cast + mask tile flags ----------
__global__ void __launch_bounds__(256) cast_mask_kernel(
    const float* __restrict__ s0, const float* __restrict__ s1, const float* __restrict__ s2,
    const float* __restrict__ s3, const float* __restrict__ s4, const float* __restrict__ s5,
    const float* __restrict__ s6,
    __hip_bfloat16* __restrict__ d0, __hip_bfloat16* __restrict__ d1,
    __hip_bfloat16* __restrict__ d2, __hip_bfloat16* __restrict__ d3,
    __hip_bfloat16* __restrict__ d4, __hip_bfloat16* __restrict__ d5,
    __hip_bfloat16* __restrict__ d6,
    const int* __restrict__ mask, unsigned* __restrict__ flags) {
  const int z = blockIdx.y;
  const int t = threadIdx.x;
  if (z == 7) {  // mask tile flags: 64q x 128k tiles
    const int kt = blockIdx.x & 15, qt = (blockIdx.x >> 4) & 31, b = (int)blockIdx.x >> 9;
    const int* base = mask + ((size_t)b * S_LEN + (size_t)qt * 64) * S_LEN + (size_t)kt * 128;
    int ok = 1;
#pragma unroll
    for (int p = 0; p < 8; ++p) {
      int idx = p * 256 + t;
      int row = idx >> 5, c4 = idx & 31;
      const int4 v = *(const int4*)(base + (size_t)row * S_LEN + c4 * 4);
      ok &= (v.x != 0) & (v.y != 0) & (v.z != 0) & (v.w != 0);
    }
    unsigned long long bl = __ballot(ok);
    __shared__ unsigned long long bw[4];
    bw[t >> 6] = bl;
    __syncthreads();
    if (t == 0) {
      unsigned all = ((bw[0] & bw[1] & bw[2] & bw[3]) == ~0ull) ? 1u : 0u;
      flags[((size_t)b * 32 + qt) * 16 + kt] = all;
    }
    return;
  }
  const float* s = (z == 0) ? s0 : (z == 1) ? s1 : (z == 2) ? s2 : (z == 3) ? s3
                 : (z == 4) ? s4 : (z == 5) ? s5 : s6;
  __hip_bfloat16* d = (z == 0) ? d0 : (z == 1) ? d1 : (z == 2) ? d2 : (z == 3) ? d3
                    : (z == 4) ? d4 : (z == 5) ? d5 : d6;
  const int n = (z < 3) ? (BATCH * S_LEN * EMB) : (EMB * EMB);
  const size_t i = ((size_t)blockIdx.x * 256 + t) * 16;
  if (i >= (size_t)n) return;
  __hip_bfloat16 tmp[16];
#pragma unroll
  for (int j = 0; j < 4; ++j) {
    const float4 v = *(const float4*)(s + i + j * 4);
    tmp[j * 4 + 0] = __float2bfloat16(v.x);
    tmp[j * 4 + 1] = __float2bfloat16(v.y);
    tmp[j * 4 + 2] = __float2bfloat16(v.z);
    tmp[j * 4 + 3] = __float2bfloat16(v.w);
  }
  *(bf16x8*)(d + i)     = *(bf16x8*)&tmp[0];
  *(bf16x8*)(d + i + 8) = *(bf16x8*)&tmp[8];
}

// ---------------- kernel 1: QKV GEMM, 128x128, BK=64, XCD-local m-tiles -----
// z=0 -> Q (scale log2e/8, [b,h,s,d]); z=1 -> K ([b,h,s,d]);
// z=2 -> V frag-packed (matches flash PV B-operand layout)
__global__ void __launch_bounds__(256, 2)
gemm_kernel(const __hip_bfloat16* __restrict__ A0, const __hip_bfloat16* __restrict__ A1,
            const __hip_bfloat16* __restrict__ A2,
            const __hip_bfloat16* __restrict__ W0, const __hip_bfloat16* __restrict__ W1,
            const __hip_bfloat16* __restrict__ W2,
            const float* __restrict__ b0, const float* __restrict__ b1,
            const float* __restrict__ b2,
            __hip_bfloat16* __restrict__ O0, __hip_bfloat16* __restrict__ O1,
            __hip_bfloat16* __restrict__ O2) {
  __shared__ __align__(16) __hip_bfloat16 As[128 * 64];
  __shared__ __align__(16) __hip_bfloat16 Bs[128 * 64];

  // XCD-local decode: m-tile index mod 8 == blockIdx%8 (A-tile reuse stays on-XCD)
  const int L = blockIdx.x;
  const int m0 = (L & 31) * 128;
  const int n0 = ((L >> 5) & 7) * 128;
  const int z  = L >> 8;

  const __hip_bfloat16* A  = (z == 0) ? A0 : ((z == 1) ? A1 : A2);
  const __hip_bfloat16* W  = (z == 0) ? W0 : ((z == 1) ? W1 : W2);
  const float* bi          = (z == 0) ? b0 : ((z == 1) ? b1 : b2);
  __hip_bfloat16* O        = (z == 0) ? O0 : ((z == 1) ? O1 : O2);

  const int t = threadIdx.x;
  const int w = t >> 6, lane = t & 63, quad = lane >> 4, l15 = lane & 15;
  const int wr = w >> 1, wc = w & 1;

  f32x4 acc[4][4];
#pragma unroll
  for (int i = 0; i < 4; ++i)
#pragma unroll
    for (int j = 0; j < 4; ++j) acc[i][j] = (f32x4)0.0f;

  const int srow = t >> 3;
  const int scb  = (t & 7) ^ (srow & 7);
  const __hip_bfloat16* Ap = A + (size_t)(m0 + srow) * EMB + (scb << 3);
  const __hip_bfloat16* Wp = W + (size_t)(n0 + srow) * EMB + (scb << 3);

  for (int k0 = 0; k0 < EMB; k0 += 64) {
    __syncthreads();
#pragma unroll
    for (int rnd = 0; rnd < 4; ++rnd) {
      gll16(Ap + (size_t)(rnd * 32) * EMB + k0, &As[(rnd * 256 + (w << 6)) * 8]);
      gll16(Wp + (size_t)(rnd * 32) * EMB + k0, &Bs[(rnd * 256 + (w << 6)) * 8]);
    }
    __syncthreads();

    bf16x8 af[4][2], bfr[4][2];
#pragma unroll
    for (int i = 0; i < 4; ++i) {
      const int ra = wr * 64 + i * 16 + l15;
#pragma unroll
      for (int hh = 0; hh < 2; ++hh)
        af[i][hh] = *(const bf16x8*)&As[ra * 64 + ((((hh << 2) + quad) ^ (l15 & 7)) << 3)];
    }
#pragma unroll
    for (int j = 0; j < 4; ++j) {
      const int rbw = wc * 64 + j * 16 + l15;
#pragma unroll
      for (int hh = 0; hh < 2; ++hh)
        bfr[j][hh] = *(const bf16x8*)&Bs[rbw * 64 + ((((hh << 2) + quad) ^ (l15 & 7)) << 3)];
    }
#pragma unroll
    for (int hh = 0; hh < 2; ++hh)
#pragma unroll
      for (int i = 0; i < 4; ++i)
#pragma unroll
        for (int j = 0; j < 4; ++j)
          acc[i][j] =
              __builtin_amdgcn_mfma_f32_16x16x32_bf16(af[i][hh], bfr[j][hh], acc[i][j], 0, 0, 0);
  }

#pragma unroll
  for (int j = 0; j < 4; ++j) {
    const int ng = n0 + wc * 64 + j * 16 + l15;
    const float bb = bi[ng];
    const int h = ng >> 6, d = ng & 63;
#pragma unroll
    for (int i = 0; i < 4; ++i) {
#pragma unroll
      for (int r = 0; r < 4; ++r) {
        const int mg = m0 + wr * 64 + i * 16 + quad * 4 + r;
        const int b = mg >> 11, s = mg & 2047;
        float v = acc[i][j][r] + bb;
        if (z == 0) {        // Q, pre-scaled by log2e/8 so flash uses raw exp2
          O[(((size_t)b * NHEAD + h) * S_LEN + s) * HDIM + d] =
              __float2bfloat16(v * (0.125f * 1.4426950408889634f));
        } else if (z == 1) { // K
          O[(((size_t)b * NHEAD + h) * S_LEN + s) * HDIM + d] = __float2bfloat16(v);
        } else {             // V frag-packed
          const size_t idx = (size_t)(b * NHEAD + h) * 131072 + (size_t)(s >> 7) * 8192 +
                             (size_t)((((s >> 5) & 3) * 4 + ((s >> 2) & 3)) * 64 + d) * 8 +
                             ((s >> 4) & 1) * 4 + (s & 3);
          O[idx] = __float2bfloat16(v);
        }
      }
    }
  }
}

// ---------------- kernel 3: output projection, 64x128, BK=64, XCD-local -----
__global__ void __launch_bounds__(256, 2)
gemm_o_kernel(const __hip_bfloat16* __restrict__ A, const __hip_bfloat16* __restrict__ W,
              const float* __restrict__ bi, float* __restrict__ O) {
  __shared__ __align__(16) __hip_bfloat16 As[64 * 64];
  __shared__ __align__(16) __hip_bfloat16 Bs[128 * 64];
  const int L = blockIdx.x;
  const int m0 = (L & 63) * 64;    // m-tile mod 8 == XCD
  const int n0 = (L >> 6) * 128;
  const int t = threadIdx.x;
  const int w = t >> 6, lane = t & 63, quad = lane >> 4, l15 = lane & 15;
  const int wr = w >> 1, wc = w & 1;

  f32x4 acc[2][4];
#pragma unroll
  for (int i = 0; i < 2; ++i)
#pragma unroll
    for (int j = 0; j < 4; ++j) acc[i][j] = (f32x4)0.0f;

  const int srow = t >> 3;
  const int scb  = (t & 7) ^ (srow & 7);
  const __hip_bfloat16* Ap = A + (size_t)(m0 + srow) * EMB + (scb << 3);
  const __hip_bfloat16* Wp = W + (size_t)(n0 + srow) * EMB + (scb << 3);

  for (int k0 = 0; k0 < EMB; k0 += 64) {
    __syncthreads();
#pragma unroll
    for (int rnd = 0; rnd < 2; ++rnd)
      gll16(Ap + (size_t)(rnd * 32) * EMB + k0, &As[(rnd * 256 + (w << 6)) * 8]);
#pragma unroll
    for (int rnd = 0; rnd < 4; ++rnd)
      gll16(Wp + (size_t)(rnd * 32) * EMB + k0, &Bs[(rnd * 256 + (w << 6)) * 8]);
    __syncthreads();

    bf16x8 af[2][2], bfr[4][2];
#pragma unroll
    for (int i = 0; i < 2; ++i) {
      const int ra = wr * 32 + i * 16 + l15;
#pragma unroll
      for (int hh = 0; hh < 2; ++hh)
        af[i][hh] = *(const bf16x8*)&As[ra * 64 + ((((hh << 2) + quad) ^ (l15 & 7)) << 3)];
    }
#pragma unroll
    for (int j = 0; j < 4; ++j) {
      const int rbw = wc * 64 + j * 16 + l15;
#pragma unroll
      for (int hh = 0; hh < 2; ++hh)
        bfr[j][hh] = *(const bf16x8*)&Bs[rbw * 64 + ((((hh << 2) + quad) ^ (l15 & 7)) << 3)];
    }
#pragma unroll
    for (int hh = 0; hh < 2; ++hh)
#pragma unroll
      for (int i = 0; i < 2; ++i)
#pragma unroll
        for (int j = 0; j < 4; ++j)
          acc[i][j] =
              __builtin_amdgcn_mfma_f32_16x16x32_bf16(af[i][hh], bfr[j][hh], acc[i][j], 0, 0, 0);
  }

#pragma unroll
  for (int j = 0; j < 4; ++j) {
    const int ng = n0 + wc * 64 + j * 16 + l15;
    const float bb = bi[ng];
#pragma unroll
    for (int i = 0; i < 2; ++i) {
#pragma unroll
      for (int r = 0; r < 4; ++r) {
        const int mg = m0 + wr * 32 + i * 16 + quad * 4 + r;
        O[(size_t)mg * EMB + ng] = acc[i][j][r] + bb;
      }
    }
  }
}

// ---------------- kernel 2: flash attention, split-K wave halves ------------
// Waves 0-3: keys 0-63 of each tile for q-band wq*32..wq*32+32; waves 4-7:
// keys 64-127 of the same q rows. K/V fragment LDS reads halved (kf/vv reused
// across 2 q-groups). fp32 partial merge via 32 KB LDS overlay at the end.
__global__ void __launch_bounds__(512, 4)
flash_kernel(const __hip_bfloat16* __restrict__ qws, const __hip_bfloat16* __restrict__ kws,
             const __hip_bfloat16* __restrict__ vpk, const int* __restrict__ responses,
             const int* __restrict__ mask, const float* __restrict__ Wm,
             const unsigned* __restrict__ flags, __hip_bfloat16* __restrict__ att) {
  __shared__ __align__(16) unsigned char smem[32768];  // Ks(16K)+Vs(16K); f32 merge overlay
  __shared__ unsigned char rb[S_LEN];                  // key responses as bytes
  __shared__ float lsm[512];                           // lo-half lsum staging

  __hip_bfloat16* Ks = (__hip_bfloat16*)smem;
  __hip_bfloat16* Vs = (__hip_bfloat16*)(smem + 16384);
  float* sm = (float*)smem;

  const int t = threadIdx.x;
  const int w = t >> 6, lane = t & 63, quad = lane >> 4, l15 = lane & 15;
  const int L = blockIdx.x;
  const int bh = L & 31;         // bh mod 8 == XCD: all q-tiles of a bh co-locate
  const int qt = L >> 5;
  const int b = bh >> 4, h = bh & 15;
  const int q0 = qt * 128;
  const int wq = w & 3, khalf = w >> 2;

#pragma unroll
  for (int i = 0; i < 4; ++i)
    rb[i * 512 + t] = (unsigned char)responses[b * S_LEN + i * 512 + t];

  // Q fragments: q rows q0+wq*32+qg*16+l15 (B-operand of transposed QK^T)
  const __hip_bfloat16* qbase = qws + ((size_t)bh * S_LEN + q0 + wq * 32) * HDIM;
  bf16x8 qf[2][2];
#pragma unroll
  for (int qg = 0; qg < 2; ++qg)
#pragma unroll
    for (int ks = 0; ks < 2; ++ks)
      qf[qg][ks] =
          *(const bf16x8*)(qbase + (size_t)(qg * 16 + l15) * HDIM + ks * 32 + quad * 8);

  const float c = Wm[h] * (0.0625f * 1.4426950408889634f);  // Wm/16 * log2e
  float A2[2];
#pragma unroll
  for (int qg = 0; qg < 2; ++qg)
    A2[qg] = 2.0f * c * (float)responses[b * S_LEN + q0 + wq * 32 + qg * 16 + l15];

  const __hip_bfloat16* kptr = kws + ((size_t)bh * S_LEN + (t >> 3)) * HDIM +
                               (((t & 7) ^ ((t >> 3) & 7)) << 3);
  const __hip_bfloat16* vptr = vpk + (size_t)bh * 131072 + (size_t)t * 8;

  float lsum[2] = {0.f, 0.f};
  f32x4 acc_o[2][4];
#pragma unroll
  for (int qg = 0; qg < 2; ++qg)
#pragma unroll
    for (int dt = 0; dt < 4; ++dt) acc_o[qg][dt] = (f32x4)0.0f;

  for (int kt = 0; kt < S_LEN / 128; ++kt) {
    __syncthreads();  // A: prior QK/PV reads of Ks/Vs complete
#pragma unroll
    for (int p = 0; p < 2; ++p) {
      gll16(kptr + p * 64 * HDIM, &Ks[(p * 512 + (w << 6)) * 8]);
      gll16(vptr + p * 4096,      &Vs[(p * 512 + (w << 6)) * 8]);
    }
    kptr += 128 * HDIM;
    vptr += 8192;
    __syncthreads();  // B: staging complete

    const unsigned fl = flags[((size_t)b * 32 + 2 * qt + (wq >> 1)) * 16 + kt];

    bf16x8 pfr[2][2];  // [qg][32-key pair-group]
#pragma unroll
    for (int ct = 0; ct < 4; ++ct) {
      const int rowk = khalf * 64 + ct * 16 + l15;
      bf16x8 kf0 = *(const bf16x8*)&Ks[rowk * 64 + ((quad ^ (l15 & 7)) << 3)];
      bf16x8 kf1 = *(const bf16x8*)&Ks[rowk * 64 + (((4 + quad) ^ (l15 & 7)) << 3)];
      const unsigned ru = *(const unsigned*)&rb[kt * 128 + khalf * 64 + ct * 16 + quad * 4];
#pragma unroll
      for (int qg = 0; qg < 2; ++qg) {
        f32x4 sc = __builtin_amdgcn_mfma_f32_16x16x32_bf16(kf0, qf[qg][0], (f32x4)0.0f, 0, 0, 0);
        sc = __builtin_amdgcn_mfma_f32_16x16x32_bf16(kf1, qf[qg][1], sc, 0, 0, 0);
        __hip_bfloat16 pb[4];
#pragma unroll
        for (int r = 0; r < 4; ++r) {
          const float rkf = (float)((ru >> (8 * r)) & 255u);
          const float sb = fmaf(rkf, fmaf(-c, rkf, A2[qg]), sc[r]);
          float p = __builtin_amdgcn_exp2f(sb);
          if (!fl) {  // slow path (all-ones mask never takes it)
            int mq = mask[((size_t)b * S_LEN + q0 + wq * 32 + qg * 16 + l15) * S_LEN +
                          kt * 128 + khalf * 64 + ct * 16 + quad * 4 + r];
            p = mq ? p : 0.0f;
          }
          lsum[qg] += p;
          pb[r] = __float2bfloat16(p);
        }
        __hip_bfloat16* half = (__hip_bfloat16*)&pfr[qg][ct >> 1] + (ct & 1) * 4;
        half[0] = pb[0]; half[1] = pb[1]; half[2] = pb[2]; half[3] = pb[3];
      }
    }

    // PV: vv loaded once per (ct2,dt), reused for both q-groups
#pragma unroll
    for (int ct2 = 0; ct2 < 2; ++ct2) {
      const int g2 = khalf * 2 + ct2;
#pragma unroll
      for (int dt = 0; dt < 4; ++dt) {
        bf16x8 vv = *(const bf16x8*)&Vs[(((g2 << 2) + quad) * 64 + (dt << 4) + l15) << 3];
#pragma unroll
        for (int qg = 0; qg < 2; ++qg)
          acc_o[qg][dt] =
              __builtin_amdgcn_mfma_f32_16x16x32_bf16(pfr[qg][ct2], vv, acc_o[qg][dt], 0, 0, 0);
      }
    }
  }

  // ---- merge the two key-halves (exact fp32 adds), normalize, store -------
  __syncthreads();  // staging region free; reuse as f32 scratch
  if (khalf == 0) {
#pragma unroll
    for (int qg = 0; qg < 2; ++qg) {
#pragma unroll
      for (int dt = 0; dt < 4; ++dt)
        *(f32x4*)&sm[((((wq << 1) + qg) << 2) + dt) * 256 + lane * 4] = acc_o[qg][dt];
      lsm[((wq << 1) + qg) * 64 + lane] = lsum[qg];
    }
  }
  __syncthreads();
  if (khalf == 1) {
#pragma unroll
    for (int qg = 0; qg < 2; ++qg) {
      lsum[qg] += lsm[((wq << 1) + qg) * 64 + lane];
      lsum[qg] += __shfl_xor(lsum[qg], 16, 64);
      lsum[qg] += __shfl_xor(lsum[qg], 32, 64);
#pragma unroll
      for (int dt = 0; dt < 4; ++dt)
        acc_o[qg][dt] += *(const f32x4*)&sm[((((wq << 1) + qg) << 2) + dt) * 256 + lane * 4];
      float inv[4];
#pragma unroll
      for (int r = 0; r < 4; ++r) inv[r] = 1.0f / __shfl(lsum[qg], quad * 4 + r, 64);
#pragma unroll
      for (int dt = 0; dt < 4; ++dt)
#pragma unroll
        for (int r = 0; r < 4; ++r)
          att[((size_t)b * S_LEN + q0 + wq * 32 + qg * 16 + quad * 4 + r) * EMB +
              h * HDIM + dt * 16 + l15] = __float2bfloat16(acc_o[qg][dt][r] * inv[r]);
    }
  }
}

// ---------------------------------------------------------------------------
extern "C" void kernel_launch(void* const* d_in, const int* in_sizes, int n_in,
                              void* d_out, int out_size, void* d_ws, size_t ws_size,
                              hipStream_t stream) {
  const float* query = (const float*)d_in[0];
  const float* key_  = (const float*)d_in[1];
  const float* value = (const float*)d_in[2];
  const int* responses = (const int*)d_in[3];
  const int* mask      = (const int*)d_in[4];
  const float* Wq = (const float*)d_in[5];
  const float* bq = (const float*)d_in[6];
  const float* Wk = (const float*)d_in[7];
  const float* bk = (const float*)d_in[8];
  const float* Wv = (const float*)d_in[9];
  const float* bv = (const float*)d_in[10];
  const float* Wo = (const float*)d_in[11];
  const float* bo = (const float*)d_in[12];
  const float* Wm = (const float*)d_in[13];
  // d_in[14] (bm): per-row constant under softmax -> exactly cancels; unused.

  __hip_bfloat16* ws = (__hip_bfloat16*)d_ws;
  const size_t NTOK = (size_t)BATCH * S_LEN * EMB;  // 4 Mi elements
  const size_t NW   = (size_t)EMB * EMB;            // 1 Mi elements
  __hip_bfloat16* qcast = ws;
  __hip_bfloat16* kcast = ws + NTOK;
  __hip_bfloat16* vcast = ws + 2 * NTOK;
  __hip_bfloat16* wqb   = ws + 3 * NTOK;
  __hip_bfloat16* wkb   = wqb + NW;
  __hip_bfloat16* wvb   = wqb + 2 * NW;
  __hip_bfloat16* wob   = wqb + 3 * NW;
  __hip_bfloat16* qws   = wqb + 4 * NW;
  __hip_bfloat16* kws   = qws + NTOK;
  __hip_bfloat16* vpk   = qws + 2 * NTOK;
  __hip_bfloat16* att   = qws + 3 * NTOK;
  unsigned* flags       = (unsigned*)(qws + 4 * NTOK);
  float* out            = (float*)d_out;

  cast_mask_kernel<<<dim3(1024, 8), 256, 0, stream>>>(
      query, key_, value, Wq, Wk, Wv, Wo,
      qcast, kcast, vcast, wqb, wkb, wvb, wob, mask, flags);
  gemm_kernel<<<768, 256, 0, stream>>>(qcast, kcast, vcast, wqb, wkb, wvb,
                                       bq, bk, bv, qws, kws, vpk);
  flash_kernel<<<512, 512, 0, stream>>>(qws, kws, vpk, responses, mask,
                                        Wm, flags, att);
  gemm_o_kernel<<<512, 256, 0, stream>>>(att, wob, bo, out);
}